// Round 1
// baseline (2247.372 us; speedup 1.0000x reference)
//
#include <hip/hip_runtime.h>
#include <math.h>

#define LRELU_SLOPE 0.2f
#define EPS 1e-16f

// ---------------- W transpose: Wt[k*M + m] = W[m*K + k] ----------------
__global__ void transpose_kernel(const float* __restrict__ W, float* __restrict__ Wt,
                                 int M, int K) {
  int idx = blockIdx.x * blockDim.x + threadIdx.x;
  if (idx >= M * K) return;
  int m = idx / K, k = idx % K;
  Wt[k * M + m] = W[idx];
}

// ---------------- GEMM: h[n, m] = sum_k x[n,k] * Wt[k, m] ----------------
// Block = M threads (one thread per output column), NPB nodes per block.
template <int K, int M, int NPB>
__global__ __launch_bounds__(M) void gemm_kernel(const float* __restrict__ x,
                                                 const float* __restrict__ Wt,
                                                 float* __restrict__ h, int N) {
  __shared__ float xs[NPB * K];
  const int tid = threadIdx.x;
  const long long nbase = (long long)blockIdx.x * NPB;
  for (int i = tid; i < NPB * K; i += M) {
    long long nn = nbase + i / K;
    xs[i] = (nn < N) ? x[nbase * K + i] : 0.f;
  }
  __syncthreads();
  float acc[NPB];
#pragma unroll
  for (int j = 0; j < NPB; j++) acc[j] = 0.f;
  for (int k0 = 0; k0 < K; k0 += 8) {
    float w[8];
#pragma unroll
    for (int kk = 0; kk < 8; kk++) w[kk] = Wt[(k0 + kk) * M + tid];
#pragma unroll
    for (int j = 0; j < NPB; j++) {
      const float4 xa = *(const float4*)&xs[j * K + k0];
      const float4 xb = *(const float4*)&xs[j * K + k0 + 4];
      acc[j] += xa.x * w[0] + xa.y * w[1] + xa.z * w[2] + xa.w * w[3] +
                xb.x * w[4] + xb.y * w[5] + xb.z * w[6] + xb.w * w[7];
    }
  }
#pragma unroll
  for (int j = 0; j < NPB; j++) {
    long long n = nbase + j;
    if (n < N) h[n * M + tid] = acc[j];
  }
}

// ---------------- per-node attention dots: one wave per node ----------------
template <int H>
__global__ void att_kernel(const float* __restrict__ h, const float* __restrict__ att_s,
                           const float* __restrict__ att_d, float* __restrict__ asrc,
                           float* __restrict__ adst, int N) {
  long long gt = (long long)blockIdx.x * blockDim.x + threadIdx.x;
  int n = (int)(gt >> 6);
  int lane = threadIdx.x & 63;
  if (n >= N) return;
  float sv[H], dv[H];
#pragma unroll
  for (int hh = 0; hh < H; hh++) {
    float hv = h[(size_t)n * (64 * H) + hh * 64 + lane];
    sv[hh] = hv * att_s[hh * 64 + lane];
    dv[hh] = hv * att_d[hh * 64 + lane];
  }
#pragma unroll
  for (int off = 32; off; off >>= 1) {
#pragma unroll
    for (int hh = 0; hh < H; hh++) {
      sv[hh] += __shfl_xor(sv[hh], off);
      dv[hh] += __shfl_xor(dv[hh], off);
    }
  }
  if (lane == 0) {
#pragma unroll
    for (int hh = 0; hh < H; hh++) {
      asrc[(size_t)n * H + hh] = sv[hh];
      adst[(size_t)n * H + hh] = dv[hh];
    }
  }
}

// ---------------- edge pass, layer2 (H=2, C=64): one wave per edge ----------------
__global__ void edge2_kernel(const int* __restrict__ ei, const float* __restrict__ h,
                             const float* __restrict__ asrc, const float* __restrict__ adst,
                             float* __restrict__ agg, float* __restrict__ denom,
                             int E, int N) {
  long long gt = (long long)blockIdx.x * blockDim.x + threadIdx.x;
  int e = (int)(gt >> 6);
  int lane = threadIdx.x & 63;
  if (e >= E + N) return;
  int s, d;
  if (e < E) {
    s = ei[e];
    d = ei[E + e];
  } else {
    s = d = e - E;
  }
  float2 as = *(const float2*)&asrc[2 * (size_t)s];
  float2 ad = *(const float2*)&adst[2 * (size_t)d];
  float e0 = as.x + ad.x;
  e0 = e0 > 0.f ? e0 : LRELU_SLOPE * e0;
  float e1 = as.y + ad.y;
  e1 = e1 > 0.f ? e1 : LRELU_SLOPE * e1;
  float p0 = __expf(e0), p1 = __expf(e1);
  float p = lane < 32 ? p0 : p1;  // cols [0,64) = head0, [64,128) = head1; lane covers 2 cols
  float2 hv = *(const float2*)&h[(size_t)s * 128 + lane * 2];
  float* dp = &agg[(size_t)d * 128 + lane * 2];
  atomicAdd(dp, p * hv.x);
  atomicAdd(dp + 1, p * hv.y);
  if (lane == 0) atomicAdd(&denom[2 * (size_t)d], p0);
  else if (lane == 32) atomicAdd(&denom[2 * (size_t)d + 1], p1);
}

// ---------------- edge pass, layer1 (H=1, C=64) ----------------
__global__ void edge1_kernel(const int* __restrict__ ei, const float* __restrict__ h,
                             const float* __restrict__ asrc, const float* __restrict__ adst,
                             float* __restrict__ agg, float* __restrict__ denom,
                             int E, int N) {
  long long gt = (long long)blockIdx.x * blockDim.x + threadIdx.x;
  int e = (int)(gt >> 6);
  int lane = threadIdx.x & 63;
  if (e >= E + N) return;
  int s, d;
  if (e < E) {
    s = ei[e];
    d = ei[E + e];
  } else {
    s = d = e - E;
  }
  float el = asrc[s] + adst[d];
  el = el > 0.f ? el : LRELU_SLOPE * el;
  float p = __expf(el);
  float hv = h[(size_t)s * 64 + lane];
  atomicAdd(&agg[(size_t)d * 64 + lane], p * hv);
  if (lane == 0) atomicAdd(&denom[d], p);
}

// ---------------- finalize: divide by denom, +bias, ELU ----------------
__global__ void finalize2_kernel(float* __restrict__ agg, const float* __restrict__ denom,
                                 const float* __restrict__ bias, int N) {
  long long idx = (long long)blockIdx.x * blockDim.x + threadIdx.x;
  if (idx >= (long long)N * 128) return;
  int n = (int)(idx >> 7), m = (int)(idx & 127), head = m >> 6;
  float v = agg[idx] / (denom[(size_t)n * 2 + head] + EPS) + bias[m];
  agg[idx] = v > 0.f ? v : expm1f(v);
}

__global__ void finalize1_kernel(const float* __restrict__ agg, const float* __restrict__ denom,
                                 const float* __restrict__ bias, float* __restrict__ out, int N) {
  long long idx = (long long)blockIdx.x * blockDim.x + threadIdx.x;
  if (idx >= (long long)N * 64) return;
  int n = (int)(idx >> 6), c = (int)(idx & 63);
  float v = agg[idx] / (denom[n] + EPS) + bias[c];
  out[idx] = v > 0.f ? v : expm1f(v);
}

extern "C" void kernel_launch(void* const* d_in, const int* in_sizes, int n_in,
                              void* d_out, int out_size, void* d_ws, size_t ws_size,
                              hipStream_t stream) {
  const float* x = (const float*)d_in[0];
  const int* ei1 = (const int*)d_in[1];
  const int* ei2 = (const int*)d_in[2];
  const float* W2 = (const float*)d_in[3];
  const float* as2 = (const float*)d_in[4];
  const float* ad2 = (const float*)d_in[5];
  const float* b2 = (const float*)d_in[6];
  const float* W1 = (const float*)d_in[7];
  const float* as1 = (const float*)d_in[8];
  const float* ad1 = (const float*)d_in[9];
  const float* b1 = (const float*)d_in[10];
  float* out = (float*)d_out;

  const int N = in_sizes[0] / 128;
  const int E1 = in_sizes[1] / 2;
  const int E2 = in_sizes[2] / 2;
  const size_t Ns = (size_t)N;

  float* ws = (float*)d_ws;
  float* Wt2 = ws;                      // 16384
  float* Wt1 = Wt2 + 16384;             // 8192
  float* asrc2 = Wt1 + 8192;            // 2N
  float* adst2 = asrc2 + 2 * Ns;        // 2N
  float* denom2 = adst2 + 2 * Ns;       // 2N
  float* asrc1 = denom2 + 2 * Ns;       // N
  float* adst1 = asrc1 + Ns;            // N
  float* denom1 = adst1 + Ns;           // N
  float* h2 = denom1 + Ns;              // 128N ; reused by layer1 as h1 (64N) + agg1 (64N)
  float* agg2 = h2 + 128 * Ns;          // 128N ; becomes hin1 in-place after finalize2
  float* h1 = h2;
  float* agg1 = h2 + 64 * Ns;

  // prep
  transpose_kernel<<<(128 * 128 + 255) / 256, 256, 0, stream>>>(W2, Wt2, 128, 128);
  transpose_kernel<<<(64 * 128 + 255) / 256, 256, 0, stream>>>(W1, Wt1, 64, 128);
  hipMemsetAsync(denom2, 0, 2 * Ns * sizeof(float), stream);
  hipMemsetAsync(denom1, 0, Ns * sizeof(float), stream);
  hipMemsetAsync(agg2, 0, 128 * Ns * sizeof(float), stream);

  // ---- layer 2: 128 -> [2 heads x 64], concat ----
  gemm_kernel<128, 128, 32><<<(N + 31) / 32, 128, 0, stream>>>(x, Wt2, h2, N);
  att_kernel<2><<<(N + 3) / 4, 256, 0, stream>>>(h2, as2, ad2, asrc2, adst2, N);
  edge2_kernel<<<((size_t)(E2 + N) + 3) / 4, 256, 0, stream>>>(ei2, h2, asrc2, adst2, agg2,
                                                               denom2, E2, N);
  finalize2_kernel<<<(Ns * 128 + 255) / 256, 256, 0, stream>>>(agg2, denom2, b2, N);

  // ---- layer 1: 128 -> 64, single head ----
  hipMemsetAsync(agg1, 0, 64 * Ns * sizeof(float), stream);
  gemm_kernel<128, 64, 32><<<(N + 31) / 32, 64, 0, stream>>>(agg2, Wt1, h1, N);
  att_kernel<1><<<(N + 3) / 4, 256, 0, stream>>>(h1, as1, ad1, asrc1, adst1, N);
  edge1_kernel<<<((size_t)(E1 + N) + 3) / 4, 256, 0, stream>>>(ei1, h1, asrc1, adst1, agg1,
                                                               denom1, E1, N);
  finalize1_kernel<<<(Ns * 64 + 255) / 256, 256, 0, stream>>>(agg1, denom1, b1, out, N);
}

// Round 2
// 1242.633 us; speedup vs baseline: 1.8086x; 1.8086x over previous
//
#include <hip/hip_runtime.h>
#include <hip/hip_bf16.h>
#include <math.h>

#define LRELU_SLOPE 0.2f
#define EPS 1e-16f

typedef __hip_bfloat16 bf16;

__device__ inline float to_f32(float v) { return v; }
__device__ inline float to_f32(bf16 v) { return __bfloat162float(v); }
__device__ inline void store_conv(float* p, float v) { *p = v; }
__device__ inline void store_conv(bf16* p, float v) { *p = __float2bfloat16(v); }
__device__ inline float lrelu(float v) { return v > 0.f ? v : LRELU_SLOPE * v; }

// ---------------- W transpose: Wt[k*M + m] = W[m*K + k] ----------------
__global__ void transpose_kernel(const float* __restrict__ W, float* __restrict__ Wt,
                                 int M, int K) {
  int idx = blockIdx.x * blockDim.x + threadIdx.x;
  if (idx >= M * K) return;
  int m = idx / K, k = idx % K;
  Wt[k * M + m] = W[idx];
}

// ---------------- CSR build ----------------
__global__ void count_kernel(const int* __restrict__ ei, int* __restrict__ deg, int E) {
  int e = blockIdx.x * blockDim.x + threadIdx.x;
  if (e >= E) return;
  atomicAdd(&deg[ei[E + e]], 1);
}

// exclusive scan of deg[N] -> rowptr[N] (start offsets), single block, chunked
__global__ __launch_bounds__(1024) void scan_kernel(const int* __restrict__ deg,
                                                    int* __restrict__ rowptr, int N) {
  __shared__ int sums[1024];
  const int tid = threadIdx.x;
  const int chunk = (N + 1023) / 1024;
  const int start = tid * chunk;
  const int end = min(start + chunk, N);
  int s = 0;
  for (int i = start; i < end; i++) s += deg[i];
  sums[tid] = s;
  __syncthreads();
  for (int off = 1; off < 1024; off <<= 1) {
    int v = (tid >= off) ? sums[tid - off] : 0;
    __syncthreads();
    sums[tid] += v;
    __syncthreads();
  }
  int run = tid ? sums[tid - 1] : 0;
  for (int i = start; i < end; i++) {
    rowptr[i] = run;
    run += deg[i];
  }
}

// fill: consumes rowptr as cursor; afterwards rowptr[d] == end offset of node d
__global__ void fill_kernel(const int* __restrict__ ei, int* __restrict__ rowptr,
                            int* __restrict__ eidx, int E) {
  int e = blockIdx.x * blockDim.x + threadIdx.x;
  if (e >= E) return;
  int s = ei[e], d = ei[E + e];
  int pos = atomicAdd(&rowptr[d], 1);
  eidx[pos] = s;
}

// ---------------- GEMM: h[n, m] = sum_k x[n,k] * Wt[k, m] ----------------
template <int K, int M, int NPB, typename Tin, typename Tout>
__global__ __launch_bounds__(M) void gemm_kernel(const Tin* __restrict__ x,
                                                 const float* __restrict__ Wt,
                                                 Tout* __restrict__ h, int N) {
  __shared__ float xs[NPB * K];
  const int tid = threadIdx.x;
  const long long nbase = (long long)blockIdx.x * NPB;
  for (int i = tid; i < NPB * K; i += M) {
    long long nn = nbase + i / K;
    xs[i] = (nn < N) ? to_f32(x[nbase * K + i]) : 0.f;
  }
  __syncthreads();
  float acc[NPB];
#pragma unroll
  for (int j = 0; j < NPB; j++) acc[j] = 0.f;
  for (int k0 = 0; k0 < K; k0 += 8) {
    float w[8];
#pragma unroll
    for (int kk = 0; kk < 8; kk++) w[kk] = Wt[(k0 + kk) * M + tid];
#pragma unroll
    for (int j = 0; j < NPB; j++) {
      const float4 xa = *(const float4*)&xs[j * K + k0];
      const float4 xb = *(const float4*)&xs[j * K + k0 + 4];
      acc[j] += xa.x * w[0] + xa.y * w[1] + xa.z * w[2] + xa.w * w[3] +
                xb.x * w[4] + xb.y * w[5] + xb.z * w[6] + xb.w * w[7];
    }
  }
#pragma unroll
  for (int j = 0; j < NPB; j++) {
    long long n = nbase + j;
    if (n < N) store_conv(&h[n * M + tid], acc[j]);
  }
}

// ---------------- per-node attention dots: one wave per node ----------------
template <int H>
__global__ void att_kernel(const bf16* __restrict__ h, const float* __restrict__ att_s,
                           const float* __restrict__ att_d, float* __restrict__ asrc,
                           float* __restrict__ adst, int N) {
  long long gt = (long long)blockIdx.x * blockDim.x + threadIdx.x;
  int n = (int)(gt >> 6);
  int lane = threadIdx.x & 63;
  if (n >= N) return;
  float sv[H], dv[H];
#pragma unroll
  for (int hh = 0; hh < H; hh++) {
    float hv = to_f32(h[(size_t)n * (64 * H) + hh * 64 + lane]);
    sv[hh] = hv * att_s[hh * 64 + lane];
    dv[hh] = hv * att_d[hh * 64 + lane];
  }
#pragma unroll
  for (int off = 32; off; off >>= 1) {
#pragma unroll
    for (int hh = 0; hh < H; hh++) {
      sv[hh] += __shfl_xor(sv[hh], off);
      dv[hh] += __shfl_xor(dv[hh], off);
    }
  }
  if (lane == 0) {
#pragma unroll
    for (int hh = 0; hh < H; hh++) {
      asrc[(size_t)n * H + hh] = sv[hh];
      adst[(size_t)n * H + hh] = dv[hh];
    }
  }
}

// ---------------- gather, layer2 (H=2, C=64): one wave per dst node ----------------
// rowptr is post-fill: rowptr[d] = end of node d; start = rowptr[d-1] (0 for d==0)
__global__ void gather2_kernel(const bf16* __restrict__ h, const float* __restrict__ asrc,
                               const float* __restrict__ adst, const int* __restrict__ rowptr,
                               const int* __restrict__ eidx, const float* __restrict__ bias,
                               float* __restrict__ outp, int N) {
  long long gt = (long long)blockIdx.x * blockDim.x + threadIdx.x;
  int n = (int)(gt >> 6);
  int lane = threadIdx.x & 63;
  if (n >= N) return;
  const float2 ad = *(const float2*)&adst[2 * (size_t)n];
  int start = n ? rowptr[n - 1] : 0;
  int end = rowptr[n];
  // self loop
  float2 as = *(const float2*)&asrc[2 * (size_t)n];
  float p0 = __expf(lrelu(as.x + ad.x));
  float p1 = __expf(lrelu(as.y + ad.y));
  float den0 = p0, den1 = p1;
  float p = lane < 32 ? p0 : p1;  // cols [0,64)=head0, [64,128)=head1; lane covers cols 2l,2l+1
  __hip_bfloat162 hv = *(const __hip_bfloat162*)&h[(size_t)n * 128 + 2 * lane];
  float acc0 = p * __bfloat162float(hv.x);
  float acc1 = p * __bfloat162float(hv.y);
  for (int j = start; j < end; j++) {
    int s = eidx[j];
    float2 a = *(const float2*)&asrc[2 * (size_t)s];
    p0 = __expf(lrelu(a.x + ad.x));
    p1 = __expf(lrelu(a.y + ad.y));
    den0 += p0;
    den1 += p1;
    p = lane < 32 ? p0 : p1;
    hv = *(const __hip_bfloat162*)&h[(size_t)s * 128 + 2 * lane];
    acc0 += p * __bfloat162float(hv.x);
    acc1 += p * __bfloat162float(hv.y);
  }
  float den = (lane < 32 ? den0 : den1) + EPS;
  int c = 2 * lane;
  float v0 = acc0 / den + bias[c];
  float v1 = acc1 / den + bias[c + 1];
  v0 = v0 > 0.f ? v0 : expm1f(v0);
  v1 = v1 > 0.f ? v1 : expm1f(v1);
  *(float2*)&outp[(size_t)n * 128 + c] = make_float2(v0, v1);
}

// ---------------- gather, layer1 (H=1, C=64): one wave per dst node ----------------
__global__ void gather1_kernel(const bf16* __restrict__ h, const float* __restrict__ asrc,
                               const float* __restrict__ adst, const int* __restrict__ rowptr,
                               const int* __restrict__ eidx, const float* __restrict__ bias,
                               float* __restrict__ outp, int N) {
  long long gt = (long long)blockIdx.x * blockDim.x + threadIdx.x;
  int n = (int)(gt >> 6);
  int lane = threadIdx.x & 63;
  if (n >= N) return;
  const float ad = adst[n];
  int start = n ? rowptr[n - 1] : 0;
  int end = rowptr[n];
  float p = __expf(lrelu(asrc[n] + ad));
  float den = p;
  float acc = p * to_f32(h[(size_t)n * 64 + lane]);
  for (int j = start; j < end; j++) {
    int s = eidx[j];
    p = __expf(lrelu(asrc[s] + ad));
    den += p;
    acc += p * to_f32(h[(size_t)s * 64 + lane]);
  }
  float v = acc / (den + EPS) + bias[lane];
  outp[(size_t)n * 64 + lane] = v > 0.f ? v : expm1f(v);
}

extern "C" void kernel_launch(void* const* d_in, const int* in_sizes, int n_in,
                              void* d_out, int out_size, void* d_ws, size_t ws_size,
                              hipStream_t stream) {
  const float* x = (const float*)d_in[0];
  const int* ei1 = (const int*)d_in[1];
  const int* ei2 = (const int*)d_in[2];
  const float* W2 = (const float*)d_in[3];
  const float* as2 = (const float*)d_in[4];
  const float* ad2 = (const float*)d_in[5];
  const float* b2 = (const float*)d_in[6];
  const float* W1 = (const float*)d_in[7];
  const float* as1 = (const float*)d_in[8];
  const float* ad1 = (const float*)d_in[9];
  const float* b1 = (const float*)d_in[10];
  float* out = (float*)d_out;

  const int N = in_sizes[0] / 128;
  const int E1 = in_sizes[1] / 2;
  const int E2 = in_sizes[2] / 2;
  const int Emax = E1 > E2 ? E1 : E2;
  const size_t Ns = (size_t)N;

  float* ws = (float*)d_ws;
  float* Wt2 = ws;                       // 16384
  float* Wt1 = Wt2 + 16384;              // 8192
  float* asrc2 = Wt1 + 8192;             // 2N
  float* adst2 = asrc2 + 2 * Ns;         // 2N
  float* asrc1 = adst2 + 2 * Ns;         // N
  float* adst1 = asrc1 + Ns;             // N
  int* deg = (int*)(adst1 + Ns);         // N
  int* rowptr = deg + Ns;                // N
  int* eidx = rowptr + Ns;               // Emax
  bf16* h2 = (bf16*)(eidx + Emax);       // 128N bf16 (64N f32-equiv)
  float* hin1 = (float*)(h2 + 128 * Ns); // 128N f32
  bf16* h1 = (bf16*)(hin1 + 128 * Ns);   // 64N bf16

  // prep
  transpose_kernel<<<(128 * 128 + 255) / 256, 256, 0, stream>>>(W2, Wt2, 128, 128);
  transpose_kernel<<<(64 * 128 + 255) / 256, 256, 0, stream>>>(W1, Wt1, 64, 128);

  // ---- layer 2: 128 -> [2 heads x 64], concat ----
  hipMemsetAsync(deg, 0, Ns * sizeof(int), stream);
  count_kernel<<<(E2 + 255) / 256, 256, 0, stream>>>(ei2, deg, E2);
  scan_kernel<<<1, 1024, 0, stream>>>(deg, rowptr, N);
  fill_kernel<<<(E2 + 255) / 256, 256, 0, stream>>>(ei2, rowptr, eidx, E2);
  gemm_kernel<128, 128, 32, float, bf16><<<(N + 31) / 32, 128, 0, stream>>>(x, Wt2, h2, N);
  att_kernel<2><<<(N + 3) / 4, 256, 0, stream>>>(h2, as2, ad2, asrc2, adst2, N);
  gather2_kernel<<<(N + 3) / 4, 256, 0, stream>>>(h2, asrc2, adst2, rowptr, eidx, b2, hin1, N);

  // ---- layer 1: 128 -> 64, single head ----
  hipMemsetAsync(deg, 0, Ns * sizeof(int), stream);
  count_kernel<<<(E1 + 255) / 256, 256, 0, stream>>>(ei1, deg, E1);
  scan_kernel<<<1, 1024, 0, stream>>>(deg, rowptr, N);
  fill_kernel<<<(E1 + 255) / 256, 256, 0, stream>>>(ei1, rowptr, eidx, E1);
  gemm_kernel<128, 64, 32, float, bf16><<<(N + 31) / 32, 64, 0, stream>>>(hin1, Wt1, h1, N);
  att_kernel<1><<<(N + 3) / 4, 256, 0, stream>>>(h1, as1, ad1, asrc1, adst1, N);
  gather1_kernel<<<(N + 3) / 4, 256, 0, stream>>>(h1, asrc1, adst1, rowptr, eidx, b1, out, N);
}

// Round 3
// 855.081 us; speedup vs baseline: 2.6283x; 1.4532x over previous
//
#include <hip/hip_runtime.h>
#include <hip/hip_bf16.h>
#include <math.h>

#define LRELU_SLOPE 0.2f
#define EPS 1e-16f

typedef __hip_bfloat16 bf16;

__device__ inline float lrelu(float v) { return v > 0.f ? v : LRELU_SLOPE * v; }
__device__ inline float bflo(unsigned u) { return __uint_as_float(u << 16); }
__device__ inline float bfhi(unsigned u) { return __uint_as_float(u & 0xffff0000u); }

// ---------------- both W transposes in one launch ----------------
__global__ void transpose_both(const float* __restrict__ W2, float* __restrict__ Wt2,
                               const float* __restrict__ W1, float* __restrict__ Wt1) {
  int idx = blockIdx.x * blockDim.x + threadIdx.x;
  if (idx < 128 * 128) {
    int m = idx >> 7, k = idx & 127;
    Wt2[k * 128 + m] = W2[idx];
  } else {
    int i = idx - 128 * 128;
    if (i < 64 * 128) {
      int m = i >> 7, k = i & 127;
      Wt1[k * 64 + m] = W1[i];
    }
  }
}

// ---------------- degree count for both layers ----------------
__global__ void count_both_kernel(const int* __restrict__ ei2, int* __restrict__ deg2, int E2,
                                  const int* __restrict__ ei1, int* __restrict__ deg1, int E1) {
  int idx = blockIdx.x * blockDim.x + threadIdx.x;
  if (idx < E2) {
    atomicAdd(&deg2[ei2[E2 + idx]], 1);
  } else if (idx < E2 + E1) {
    int e = idx - E2;
    atomicAdd(&deg1[ei1[E1 + e]], 1);
  }
}

// exclusive scan; block 0 -> layer2, block 1 -> layer1
__global__ __launch_bounds__(1024) void scan_both_kernel(const int* __restrict__ deg2,
                                                         int* __restrict__ rowptr2,
                                                         const int* __restrict__ deg1,
                                                         int* __restrict__ rowptr1, int N) {
  const int* deg = blockIdx.x ? deg1 : deg2;
  int* rowptr = blockIdx.x ? rowptr1 : rowptr2;
  __shared__ int sums[1024];
  const int tid = threadIdx.x;
  const int chunk = (N + 1023) / 1024;
  const int start = tid * chunk;
  const int end = min(start + chunk, N);
  int s = 0;
  for (int i = start; i < end; i++) s += deg[i];
  sums[tid] = s;
  __syncthreads();
  for (int off = 1; off < 1024; off <<= 1) {
    int v = (tid >= off) ? sums[tid - off] : 0;
    __syncthreads();
    sums[tid] += v;
    __syncthreads();
  }
  int run = tid ? sums[tid - 1] : 0;
  for (int i = start; i < end; i++) {
    rowptr[i] = run;
    run += deg[i];
  }
}

// ---------------- fill CSR + per-edge softmax numerator (layer2, H=2) ----------------
__global__ void fillp2_kernel(const int* __restrict__ ei, const float* __restrict__ asrc,
                              const float* __restrict__ adst, int* __restrict__ rowptr,
                              int* __restrict__ eidx, float2* __restrict__ pcsr, int E) {
  int e = blockIdx.x * blockDim.x + threadIdx.x;
  if (e >= E) return;
  int s = ei[e], d = ei[E + e];
  int pos = atomicAdd(&rowptr[d], 1);
  eidx[pos] = s;
  float2 a = *(const float2*)&asrc[2 * (size_t)s];
  float2 b = *(const float2*)&adst[2 * (size_t)d];
  float2 pv;
  pv.x = __expf(lrelu(a.x + b.x));
  pv.y = __expf(lrelu(a.y + b.y));
  pcsr[pos] = pv;
}

// ---------------- fill CSR + per-edge softmax numerator (layer1, H=1) ----------------
__global__ void fillp1_kernel(const int* __restrict__ ei, const float* __restrict__ asrc,
                              const float* __restrict__ adst, int* __restrict__ rowptr,
                              int* __restrict__ eidx, float* __restrict__ pcsr, int E) {
  int e = blockIdx.x * blockDim.x + threadIdx.x;
  if (e >= E) return;
  int s = ei[e], d = ei[E + e];
  int pos = atomicAdd(&rowptr[d], 1);
  eidx[pos] = s;
  pcsr[pos] = __expf(lrelu(asrc[s] + adst[d]));
}

// ---------------- GEMM (h = x @ Wt) + fused att dot-products ----------------
// Block = M threads (thread = output col), NPB nodes per block.
template <int K, int M, int NPB, int H, typename Tin>
__global__ __launch_bounds__(M) void gemm_att_kernel(
    const Tin* __restrict__ x, const float* __restrict__ Wt, const float* __restrict__ atts,
    const float* __restrict__ attd, bf16* __restrict__ h, float* __restrict__ asrc,
    float* __restrict__ adst, int N) {
  __shared__ float xs[NPB * (K + 1)];  // staging uses stride K; epilogue uses stride M+1
  const int tid = threadIdx.x;
  const long long nbase = (long long)blockIdx.x * NPB;
  const bool full = (nbase + NPB) <= (long long)N;

  if constexpr (sizeof(Tin) == 4) {
    const float4* xv = (const float4*)(x + nbase * K);
    constexpr int CNT = NPB * K / 4;
    for (int i = tid; i < CNT; i += M) {
      float4 v = make_float4(0.f, 0.f, 0.f, 0.f);
      if (full || (nbase + (i * 4) / K) < N) v = xv[i];
      *(float4*)&xs[i * 4] = v;
    }
  } else {
    const uint4* xv = (const uint4*)((const unsigned short*)x + nbase * K);
    constexpr int CNT = NPB * K / 8;
    for (int i = tid; i < CNT; i += M) {
      uint4 v = make_uint4(0, 0, 0, 0);
      if (full || (nbase + (i * 8) / K) < N) v = xv[i];
      float* dst = &xs[i * 8];
      dst[0] = bflo(v.x); dst[1] = bfhi(v.x);
      dst[2] = bflo(v.y); dst[3] = bfhi(v.y);
      dst[4] = bflo(v.z); dst[5] = bfhi(v.z);
      dst[6] = bflo(v.w); dst[7] = bfhi(v.w);
    }
  }
  __syncthreads();

  float acc[NPB];
#pragma unroll
  for (int j = 0; j < NPB; j++) acc[j] = 0.f;
  for (int k0 = 0; k0 < K; k0 += 8) {
    float w[8];
#pragma unroll
    for (int kk = 0; kk < 8; kk++) w[kk] = Wt[(k0 + kk) * M + tid];
#pragma unroll
    for (int j = 0; j < NPB; j++) {
      const float4 xa = *(const float4*)&xs[j * K + k0];
      const float4 xb = *(const float4*)&xs[j * K + k0 + 4];
      acc[j] += xa.x * w[0] + xa.y * w[1] + xa.z * w[2] + xa.w * w[3] +
                xb.x * w[4] + xb.y * w[5] + xb.z * w[6] + xb.w * w[7];
    }
  }

#pragma unroll
  for (int j = 0; j < NPB; j++) {
    long long n = nbase + j;
    if (full || n < N) h[n * M + tid] = __float2bfloat16(acc[j]);
  }

  // ---- fused att: a_src[n,hh] = sum_c h[n,c]*atts[c] (c in head hh) ----
  __syncthreads();  // done reading xs in staging layout
#pragma unroll
  for (int j = 0; j < NPB; j++) xs[j * (M + 1) + tid] = acc[j];
  __syncthreads();
  constexpr int TPN = M / NPB;  // threads per node: 4 (M=128) or 2 (M=64)
  constexpr int CPT = M / TPN;  // cols per thread: 32
  const int node = tid / TPN;
  const int part = tid % TPN;
  const long long n = nbase + node;
  if (full || n < N) {
    const int c0 = part * CPT;
    float ssum = 0.f, dsum = 0.f;
#pragma unroll
    for (int cc = 0; cc < CPT; cc++) {
      int c = c0 + cc;
      float hv = xs[node * (M + 1) + c];
      ssum += hv * atts[c];
      dsum += hv * attd[c];
    }
    ssum += __shfl_xor(ssum, 1);
    dsum += __shfl_xor(dsum, 1);
    if constexpr (TPN == 4) {
      if ((part & 1) == 0) {
        int head = part >> 1;  // parts {0,1}->head0, {2,3}->head1
        asrc[n * H + head] = ssum;
        adst[n * H + head] = dsum;
      }
    } else {
      if (part == 0) {
        asrc[n] = ssum;
        adst[n] = dsum;
      }
    }
  }
}

// ---------------- gather, layer2 (H=2, C=64): one wave per dst node ----------------
__global__ void gather2_kernel(const bf16* __restrict__ h, const float* __restrict__ asrc,
                               const float* __restrict__ adst, const int* __restrict__ rowptr,
                               const int* __restrict__ eidx, const float2* __restrict__ pcsr,
                               const float* __restrict__ bias, bf16* __restrict__ outp, int N) {
  long long gt = (long long)blockIdx.x * blockDim.x + threadIdx.x;
  int n = (int)(gt >> 6);
  int lane = threadIdx.x & 63;
  if (n >= N) return;
  int start = n ? rowptr[n - 1] : 0;
  int end = rowptr[n];
  const float2 as = *(const float2*)&asrc[2 * (size_t)n];
  const float2 ad = *(const float2*)&adst[2 * (size_t)n];
  float p0 = __expf(lrelu(as.x + ad.x));
  float p1 = __expf(lrelu(as.y + ad.y));
  float den0 = p0, den1 = p1;
  const bool h0 = lane < 32;  // cols 2*lane,2*lane+1 -> head0 iff lane<32
  float p = h0 ? p0 : p1;
  unsigned hv = *(const unsigned*)&h[(size_t)n * 128 + 2 * lane];
  float acc0 = p * bflo(hv), acc1 = p * bfhi(hv);
  int j = start;
  for (; j + 1 < end; j += 2) {
    int sA = eidx[j], sB = eidx[j + 1];
    float2 pA = pcsr[j], pB = pcsr[j + 1];
    unsigned hA = *(const unsigned*)&h[(size_t)sA * 128 + 2 * lane];
    unsigned hB = *(const unsigned*)&h[(size_t)sB * 128 + 2 * lane];
    den0 += pA.x + pB.x;
    den1 += pA.y + pB.y;
    float pa = h0 ? pA.x : pA.y;
    float pb = h0 ? pB.x : pB.y;
    acc0 += pa * bflo(hA) + pb * bflo(hB);
    acc1 += pa * bfhi(hA) + pb * bfhi(hB);
  }
  if (j < end) {
    int sA = eidx[j];
    float2 pA = pcsr[j];
    unsigned hA = *(const unsigned*)&h[(size_t)sA * 128 + 2 * lane];
    den0 += pA.x;
    den1 += pA.y;
    float pa = h0 ? pA.x : pA.y;
    acc0 += pa * bflo(hA);
    acc1 += pa * bfhi(hA);
  }
  float den = (h0 ? den0 : den1) + EPS;
  int c = 2 * lane;
  float v0 = acc0 / den + bias[c];
  float v1 = acc1 / den + bias[c + 1];
  v0 = v0 > 0.f ? v0 : expm1f(v0);
  v1 = v1 > 0.f ? v1 : expm1f(v1);
  __hip_bfloat162 o;
  o.x = __float2bfloat16(v0);
  o.y = __float2bfloat16(v1);
  *(__hip_bfloat162*)&outp[(size_t)n * 128 + c] = o;
}

// ---------------- gather, layer1 (H=1, C=64): one wave per dst node ----------------
__global__ void gather1_kernel(const bf16* __restrict__ h, const float* __restrict__ asrc,
                               const float* __restrict__ adst, const int* __restrict__ rowptr,
                               const int* __restrict__ eidx, const float* __restrict__ pcsr,
                               const float* __restrict__ bias, float* __restrict__ outp, int N) {
  long long gt = (long long)blockIdx.x * blockDim.x + threadIdx.x;
  int n = (int)(gt >> 6);
  int lane = threadIdx.x & 63;
  if (n >= N) return;
  int start = n ? rowptr[n - 1] : 0;
  int end = rowptr[n];
  float p = __expf(lrelu(asrc[n] + adst[n]));
  float den = p;
  float acc = p * __bfloat162float(h[(size_t)n * 64 + lane]);
  int j = start;
  for (; j + 1 < end; j += 2) {
    int sA = eidx[j], sB = eidx[j + 1];
    float pA = pcsr[j], pB = pcsr[j + 1];
    float hA = __bfloat162float(h[(size_t)sA * 64 + lane]);
    float hB = __bfloat162float(h[(size_t)sB * 64 + lane]);
    den += pA + pB;
    acc += pA * hA + pB * hB;
  }
  if (j < end) {
    int sA = eidx[j];
    float pA = pcsr[j];
    den += pA;
    acc += pA * __bfloat162float(h[(size_t)sA * 64 + lane]);
  }
  float v = acc / (den + EPS) + bias[lane];
  outp[(size_t)n * 64 + lane] = v > 0.f ? v : expm1f(v);
}

extern "C" void kernel_launch(void* const* d_in, const int* in_sizes, int n_in,
                              void* d_out, int out_size, void* d_ws, size_t ws_size,
                              hipStream_t stream) {
  const float* x = (const float*)d_in[0];
  const int* ei1 = (const int*)d_in[1];
  const int* ei2 = (const int*)d_in[2];
  const float* W2 = (const float*)d_in[3];
  const float* as2 = (const float*)d_in[4];
  const float* ad2 = (const float*)d_in[5];
  const float* b2 = (const float*)d_in[6];
  const float* W1 = (const float*)d_in[7];
  const float* as1 = (const float*)d_in[8];
  const float* ad1 = (const float*)d_in[9];
  const float* b1 = (const float*)d_in[10];
  float* out = (float*)d_out;

  const int N = in_sizes[0] / 128;
  const int E1 = in_sizes[1] / 2;
  const int E2 = in_sizes[2] / 2;
  const int Emax = E1 > E2 ? E1 : E2;
  const size_t Ns = (size_t)N;
  const size_t Es = (size_t)Emax;

  float* ws = (float*)d_ws;
  size_t o = 0;
  float* Wt2 = ws + o;    o += 16384;
  float* Wt1 = ws + o;    o += 8192;
  float* asrc2 = ws + o;  o += 2 * Ns;
  float* adst2 = ws + o;  o += 2 * Ns;
  float* asrc1 = ws + o;  o += Ns;
  float* adst1 = ws + o;  o += Ns;
  int* deg2 = (int*)(ws + o);    o += Ns;
  int* deg1 = (int*)(ws + o);    o += Ns;
  int* rowptr2 = (int*)(ws + o); o += Ns;
  int* rowptr1 = (int*)(ws + o); o += Ns;
  o = (o + 7) & ~(size_t)7;
  float2* pcsr2 = (float2*)(ws + o);  o += 2 * Es;  // pcsr1 aliases (layer1 after layer2 done)
  float* pcsr1 = (float*)pcsr2;
  int* eidx2 = (int*)(ws + o);        o += Es;      // eidx1 aliases
  int* eidx1 = eidx2;
  o = (o + 7) & ~(size_t)7;
  bf16* h2 = (bf16*)(ws + o);         o += 64 * Ns;  // 128N bf16; h1 aliases (h2 dead after gather2)
  bf16* h1 = h2;
  bf16* hin1 = (bf16*)(ws + o);       o += 64 * Ns;  // 128N bf16

  // prep (input-only dependencies)
  transpose_both<<<(128 * 128 + 64 * 128 + 255) / 256, 256, 0, stream>>>(W2, Wt2, W1, Wt1);
  hipMemsetAsync(deg2, 0, 2 * Ns * sizeof(int), stream);  // deg2+deg1 adjacent
  count_both_kernel<<<(E2 + E1 + 255) / 256, 256, 0, stream>>>(ei2, deg2, E2, ei1, deg1, E1);
  scan_both_kernel<<<2, 1024, 0, stream>>>(deg2, rowptr2, deg1, rowptr1, N);

  // ---- layer 2: 128 -> [2 heads x 64], concat ----
  gemm_att_kernel<128, 128, 32, 2, float>
      <<<(N + 31) / 32, 128, 0, stream>>>(x, Wt2, as2, ad2, h2, asrc2, adst2, N);
  fillp2_kernel<<<(E2 + 255) / 256, 256, 0, stream>>>(ei2, asrc2, adst2, rowptr2, eidx2, pcsr2, E2);
  gather2_kernel<<<(N + 3) / 4, 256, 0, stream>>>(h2, asrc2, adst2, rowptr2, eidx2, pcsr2, b2,
                                                  hin1, N);

  // ---- layer 1: 128 -> 64, single head ----
  gemm_att_kernel<128, 64, 32, 1, bf16>
      <<<(N + 31) / 32, 64, 0, stream>>>(hin1, Wt1, as1, ad1, h1, asrc1, adst1, N);
  fillp1_kernel<<<(E1 + 255) / 256, 256, 0, stream>>>(ei1, asrc1, adst1, rowptr1, eidx1, pcsr1, E1);
  gather1_kernel<<<(N + 3) / 4, 256, 0, stream>>>(h1, asrc1, adst1, rowptr1, eidx1, pcsr1, b1, out,
                                                  N);
}

// Round 4
// 713.264 us; speedup vs baseline: 3.1508x; 1.1988x over previous
//
#include <hip/hip_runtime.h>
#include <hip/hip_bf16.h>
#include <math.h>

#define LRELU_SLOPE 0.2f
#define EPS 1e-16f
#define SCH 2048

typedef __hip_bfloat16 bf16;

__device__ inline float lrelu(float v) { return v > 0.f ? v : LRELU_SLOPE * v; }
__device__ inline float bflo(unsigned u) { return __uint_as_float(u << 16); }
__device__ inline float bfhi(unsigned u) { return __uint_as_float(u & 0xffff0000u); }

// ---------------- both W transposes in one launch ----------------
__global__ void transpose_both(const float* __restrict__ W2, float* __restrict__ Wt2,
                               const float* __restrict__ W1, float* __restrict__ Wt1) {
  int idx = blockIdx.x * blockDim.x + threadIdx.x;
  if (idx < 128 * 128) {
    int m = idx >> 7, k = idx & 127;
    Wt2[k * 128 + m] = W2[idx];
  } else {
    int i = idx - 128 * 128;
    if (i < 64 * 128) {
      int m = i >> 7, k = i & 127;
      Wt1[k * 64 + m] = W1[i];
    }
  }
}

// ---------------- degree count for both layers (deg = [deg2|deg1] concatenated) ----------------
__global__ void count_both_kernel(const int* __restrict__ ei2, int* __restrict__ deg2, int E2,
                                  const int* __restrict__ ei1, int* __restrict__ deg1, int E1) {
  int idx = blockIdx.x * blockDim.x + threadIdx.x;
  if (idx < E2) {
    atomicAdd(&deg2[ei2[E2 + idx]], 1);
  } else if (idx < E2 + E1) {
    int e = idx - E2;
    atomicAdd(&deg1[ei1[E1 + e]], 1);
  }
}

// ---------------- multi-block exclusive scan, phase A: per-chunk sums ----------------
__global__ __launch_bounds__(256) void scan_partial_kernel(const int* __restrict__ deg,
                                                           int* __restrict__ bsum) {
  const int tid = threadIdx.x;
  const int base = blockIdx.x * SCH + tid * 8;
  int4 a = *(const int4*)&deg[base];
  int4 b = *(const int4*)&deg[base + 4];
  int s = a.x + a.y + a.z + a.w + b.x + b.y + b.z + b.w;
#pragma unroll
  for (int off = 32; off; off >>= 1) s += __shfl_xor(s, off);
  __shared__ int wsum[4];
  if ((tid & 63) == 0) wsum[tid >> 6] = s;
  __syncthreads();
  if (tid == 0) bsum[blockIdx.x] = wsum[0] + wsum[1] + wsum[2] + wsum[3];
}

// ---------------- phase B+C: block prefix from bsum + in-block exclusive scan ----------------
// rowptr base covers [rowptr2 (N) | rowptr1 (N)] adjacent; layer1 entries get -E2 bias.
__global__ __launch_bounds__(256) void scan_apply_kernel(const int* __restrict__ deg,
                                                         const int* __restrict__ bsum,
                                                         int* __restrict__ rowptr, int N2, int N,
                                                         int E2) {
  const int tid = threadIdx.x;
  const int lane = tid & 63;
  const int wid = tid >> 6;
  __shared__ int sprefix;
  __shared__ int wsum[4];
  if (tid < 64) {
    int s = 0;
    for (int i = tid; i < (int)blockIdx.x; i += 64) s += bsum[i];
#pragma unroll
    for (int off = 32; off; off >>= 1) s += __shfl_xor(s, off);
    if (tid == 0) sprefix = s;
  }
  const int base = blockIdx.x * SCH + tid * 8;
  int4 a = *(const int4*)&deg[base];
  int4 b = *(const int4*)&deg[base + 4];
  int e[8] = {a.x, a.y, a.z, a.w, b.x, b.y, b.z, b.w};
  int pre[8];
  int run = 0;
#pragma unroll
  for (int k = 0; k < 8; k++) {
    pre[k] = run;
    run += e[k];
  }
  const int s8 = run;
  int inc = s8;
#pragma unroll
  for (int off = 1; off < 64; off <<= 1) {
    int t = __shfl_up(inc, off);
    if (lane >= off) inc += t;
  }
  if (lane == 63) wsum[wid] = inc;
  __syncthreads();
  int tbase = sprefix + inc - s8;
  for (int w = 0; w < wid; w++) tbase += wsum[w];
#pragma unroll
  for (int g = 0; g < 8; g += 4) {
    int i0 = base + g;
    if (i0 + 3 < N2 && ((i0 < N) == (i0 + 3 < N))) {
      int adj = (i0 >= N) ? E2 : 0;
      int4 w = make_int4(tbase + pre[g] - adj, tbase + pre[g + 1] - adj, tbase + pre[g + 2] - adj,
                         tbase + pre[g + 3] - adj);
      *(int4*)&rowptr[i0] = w;
    } else {
#pragma unroll
      for (int k = 0; k < 4; k++) {
        int i = i0 + k;
        if (i < N2) rowptr[i] = tbase + pre[g + k] - ((i >= N) ? E2 : 0);
      }
    }
  }
}

// ---------------- fill CSR + per-edge softmax numerator (layer2, H=2) ----------------
__global__ void fillp2_kernel(const int* __restrict__ ei, const float* __restrict__ asrc,
                              const float* __restrict__ adst, int* __restrict__ rowptr,
                              int* __restrict__ eidx, float2* __restrict__ pcsr, int E) {
  int e = blockIdx.x * blockDim.x + threadIdx.x;
  if (e >= E) return;
  int s = ei[e], d = ei[E + e];
  int pos = atomicAdd(&rowptr[d], 1);
  eidx[pos] = s;
  float2 a = *(const float2*)&asrc[2 * (size_t)s];
  float2 b = *(const float2*)&adst[2 * (size_t)d];
  float2 pv;
  pv.x = __expf(lrelu(a.x + b.x));
  pv.y = __expf(lrelu(a.y + b.y));
  pcsr[pos] = pv;
}

// ---------------- fill CSR + per-edge softmax numerator (layer1, H=1) ----------------
__global__ void fillp1_kernel(const int* __restrict__ ei, const float* __restrict__ asrc,
                              const float* __restrict__ adst, int* __restrict__ rowptr,
                              int* __restrict__ eidx, float* __restrict__ pcsr, int E) {
  int e = blockIdx.x * blockDim.x + threadIdx.x;
  if (e >= E) return;
  int s = ei[e], d = ei[E + e];
  int pos = atomicAdd(&rowptr[d], 1);
  eidx[pos] = s;
  pcsr[pos] = __expf(lrelu(asrc[s] + adst[d]));
}

// ---------------- GEMM (h = x @ Wt) + fused att dot-products ----------------
// Block = M threads (thread = output col), NPB nodes per block.
template <int K, int M, int NPB, int H, typename Tin>
__global__ __launch_bounds__(M) void gemm_att_kernel(
    const Tin* __restrict__ x, const float* __restrict__ Wt, const float* __restrict__ atts,
    const float* __restrict__ attd, bf16* __restrict__ h, float* __restrict__ asrc,
    float* __restrict__ adst, int N) {
  __shared__ float xs[NPB * (K + 1)];  // staging uses stride K; epilogue uses stride M+1
  const int tid = threadIdx.x;
  const long long nbase = (long long)blockIdx.x * NPB;
  const bool full = (nbase + NPB) <= (long long)N;

  if constexpr (sizeof(Tin) == 4) {
    const float4* xv = (const float4*)(x + nbase * K);
    constexpr int CNT = NPB * K / 4;
    for (int i = tid; i < CNT; i += M) {
      float4 v = make_float4(0.f, 0.f, 0.f, 0.f);
      if (full || (nbase + (i * 4) / K) < N) v = xv[i];
      *(float4*)&xs[i * 4] = v;
    }
  } else {
    const uint4* xv = (const uint4*)((const unsigned short*)x + nbase * K);
    constexpr int CNT = NPB * K / 8;
    for (int i = tid; i < CNT; i += M) {
      uint4 v = make_uint4(0, 0, 0, 0);
      if (full || (nbase + (i * 8) / K) < N) v = xv[i];
      float* dst = &xs[i * 8];
      dst[0] = bflo(v.x); dst[1] = bfhi(v.x);
      dst[2] = bflo(v.y); dst[3] = bfhi(v.y);
      dst[4] = bflo(v.z); dst[5] = bfhi(v.z);
      dst[6] = bflo(v.w); dst[7] = bfhi(v.w);
    }
  }
  __syncthreads();

  float acc[NPB];
#pragma unroll
  for (int j = 0; j < NPB; j++) acc[j] = 0.f;
  for (int k0 = 0; k0 < K; k0 += 8) {
    float w[8];
#pragma unroll
    for (int kk = 0; kk < 8; kk++) w[kk] = Wt[(k0 + kk) * M + tid];
#pragma unroll
    for (int j = 0; j < NPB; j++) {
      const float4 xa = *(const float4*)&xs[j * K + k0];
      const float4 xb = *(const float4*)&xs[j * K + k0 + 4];
      acc[j] += xa.x * w[0] + xa.y * w[1] + xa.z * w[2] + xa.w * w[3] +
                xb.x * w[4] + xb.y * w[5] + xb.z * w[6] + xb.w * w[7];
    }
  }

#pragma unroll
  for (int j = 0; j < NPB; j++) {
    long long n = nbase + j;
    if (full || n < N) h[n * M + tid] = __float2bfloat16(acc[j]);
  }

  // ---- fused att: a_src[n,hh] = sum_c h[n,c]*atts[c] (c in head hh) ----
  __syncthreads();  // done reading xs in staging layout
#pragma unroll
  for (int j = 0; j < NPB; j++) xs[j * (M + 1) + tid] = acc[j];
  __syncthreads();
  constexpr int TPN = M / NPB;  // threads per node: 4 (M=128) or 2 (M=64)
  constexpr int CPT = M / TPN;  // cols per thread: 32
  const int node = tid / TPN;
  const int part = tid % TPN;
  const long long n = nbase + node;
  if (full || n < N) {
    const int c0 = part * CPT;
    float ssum = 0.f, dsum = 0.f;
#pragma unroll
    for (int cc = 0; cc < CPT; cc++) {
      int c = c0 + cc;
      float hv = xs[node * (M + 1) + c];
      ssum += hv * atts[c];
      dsum += hv * attd[c];
    }
    ssum += __shfl_xor(ssum, 1);
    dsum += __shfl_xor(dsum, 1);
    if constexpr (TPN == 4) {
      if ((part & 1) == 0) {
        int head = part >> 1;  // parts {0,1}->head0, {2,3}->head1
        asrc[n * H + head] = ssum;
        adst[n * H + head] = dsum;
      }
    } else {
      if (part == 0) {
        asrc[n] = ssum;
        adst[n] = dsum;
      }
    }
  }
}

// ---------------- gather, layer2 (H=2, C=64): one wave per dst node ----------------
__global__ void gather2_kernel(const bf16* __restrict__ h, const float* __restrict__ asrc,
                               const float* __restrict__ adst, const int* __restrict__ rowptr,
                               const int* __restrict__ eidx, const float2* __restrict__ pcsr,
                               const float* __restrict__ bias, bf16* __restrict__ outp, int N) {
  long long gt = (long long)blockIdx.x * blockDim.x + threadIdx.x;
  int n = (int)(gt >> 6);
  int lane = threadIdx.x & 63;
  if (n >= N) return;
  int start = n ? rowptr[n - 1] : 0;
  int end = rowptr[n];
  const float2 as = *(const float2*)&asrc[2 * (size_t)n];
  const float2 ad = *(const float2*)&adst[2 * (size_t)n];
  float p0 = __expf(lrelu(as.x + ad.x));
  float p1 = __expf(lrelu(as.y + ad.y));
  float den0 = p0, den1 = p1;
  const bool h0 = lane < 32;  // cols 2*lane,2*lane+1 -> head0 iff lane<32
  float p = h0 ? p0 : p1;
  unsigned hv = *(const unsigned*)&h[(size_t)n * 128 + 2 * lane];
  float acc0 = p * bflo(hv), acc1 = p * bfhi(hv);
  int j = start;
  for (; j + 1 < end; j += 2) {
    int sA = eidx[j], sB = eidx[j + 1];
    float2 pA = pcsr[j], pB = pcsr[j + 1];
    unsigned hA = *(const unsigned*)&h[(size_t)sA * 128 + 2 * lane];
    unsigned hB = *(const unsigned*)&h[(size_t)sB * 128 + 2 * lane];
    den0 += pA.x + pB.x;
    den1 += pA.y + pB.y;
    float pa = h0 ? pA.x : pA.y;
    float pb = h0 ? pB.x : pB.y;
    acc0 += pa * bflo(hA) + pb * bflo(hB);
    acc1 += pa * bfhi(hA) + pb * bfhi(hB);
  }
  if (j < end) {
    int sA = eidx[j];
    float2 pA = pcsr[j];
    unsigned hA = *(const unsigned*)&h[(size_t)sA * 128 + 2 * lane];
    den0 += pA.x;
    den1 += pA.y;
    float pa = h0 ? pA.x : pA.y;
    acc0 += pa * bflo(hA);
    acc1 += pa * bfhi(hA);
  }
  float den = (h0 ? den0 : den1) + EPS;
  int c = 2 * lane;
  float v0 = acc0 / den + bias[c];
  float v1 = acc1 / den + bias[c + 1];
  v0 = v0 > 0.f ? v0 : expm1f(v0);
  v1 = v1 > 0.f ? v1 : expm1f(v1);
  __hip_bfloat162 o;
  o.x = __float2bfloat16(v0);
  o.y = __float2bfloat16(v1);
  *(__hip_bfloat162*)&outp[(size_t)n * 128 + c] = o;
}

// ---------------- gather, layer1 (H=1, C=64): one wave per dst node ----------------
__global__ void gather1_kernel(const bf16* __restrict__ h, const float* __restrict__ asrc,
                               const float* __restrict__ adst, const int* __restrict__ rowptr,
                               const int* __restrict__ eidx, const float* __restrict__ pcsr,
                               const float* __restrict__ bias, float* __restrict__ outp, int N) {
  long long gt = (long long)blockIdx.x * blockDim.x + threadIdx.x;
  int n = (int)(gt >> 6);
  int lane = threadIdx.x & 63;
  if (n >= N) return;
  int start = n ? rowptr[n - 1] : 0;
  int end = rowptr[n];
  float p = __expf(lrelu(asrc[n] + adst[n]));
  float den = p;
  float acc = p * __bfloat162float(h[(size_t)n * 64 + lane]);
  int j = start;
  for (; j + 1 < end; j += 2) {
    int sA = eidx[j], sB = eidx[j + 1];
    float pA = pcsr[j], pB = pcsr[j + 1];
    float hA = __bfloat162float(h[(size_t)sA * 64 + lane]);
    float hB = __bfloat162float(h[(size_t)sB * 64 + lane]);
    den += pA + pB;
    acc += pA * hA + pB * hB;
  }
  if (j < end) {
    int sA = eidx[j];
    float pA = pcsr[j];
    den += pA;
    acc += pA * __bfloat162float(h[(size_t)sA * 64 + lane]);
  }
  float v = acc / (den + EPS) + bias[lane];
  outp[(size_t)n * 64 + lane] = v > 0.f ? v : expm1f(v);
}

extern "C" void kernel_launch(void* const* d_in, const int* in_sizes, int n_in,
                              void* d_out, int out_size, void* d_ws, size_t ws_size,
                              hipStream_t stream) {
  const float* x = (const float*)d_in[0];
  const int* ei1 = (const int*)d_in[1];
  const int* ei2 = (const int*)d_in[2];
  const float* W2 = (const float*)d_in[3];
  const float* as2 = (const float*)d_in[4];
  const float* ad2 = (const float*)d_in[5];
  const float* b2 = (const float*)d_in[6];
  const float* W1 = (const float*)d_in[7];
  const float* as1 = (const float*)d_in[8];
  const float* ad1 = (const float*)d_in[9];
  const float* b1 = (const float*)d_in[10];
  float* out = (float*)d_out;

  const int N = in_sizes[0] / 128;
  const int E1 = in_sizes[1] / 2;
  const int E2 = in_sizes[2] / 2;
  const int Emax = E1 > E2 ? E1 : E2;
  const size_t Ns = (size_t)N;
  const size_t Es = (size_t)Emax;
  const int N2 = 2 * N;
  const int nb = (N2 + SCH - 1) / SCH;
  const size_t degPad = (size_t)nb * SCH;

  float* ws = (float*)d_ws;
  size_t o = 0;
  float* Wt2 = ws + o;    o += 16384;
  float* Wt1 = ws + o;    o += 8192;
  float* asrc2 = ws + o;  o += 2 * Ns;
  float* adst2 = ws + o;  o += 2 * Ns;
  float* asrc1 = ws + o;  o += Ns;
  float* adst1 = ws + o;  o += Ns;
  o = (o + 3) & ~(size_t)3;
  int* deg = (int*)(ws + o);     o += degPad;   // [deg2 (N) | deg1 (N) | zero pad]
  int* deg2 = deg;
  int* deg1 = deg + Ns;
  int* bsum = (int*)(ws + o);    o += (size_t)nb;
  o = (o + 3) & ~(size_t)3;
  int* rowptr2 = (int*)(ws + o); o += Ns;       // rowptr1 adjacent: scan_apply writes both
  int* rowptr1 = (int*)(ws + o); o += Ns;
  o = (o + 7) & ~(size_t)7;
  float2* pcsr2 = (float2*)(ws + o);  o += 2 * Es;  // pcsr1 aliases (layer1 after layer2 done)
  float* pcsr1 = (float*)pcsr2;
  int* eidx2 = (int*)(ws + o);        o += Es;      // eidx1 aliases
  int* eidx1 = eidx2;
  o = (o + 7) & ~(size_t)7;
  bf16* h2 = (bf16*)(ws + o);         o += 64 * Ns;  // 128N bf16; h1 aliases (h2 dead after gather2)
  bf16* h1 = h2;
  bf16* hin1 = (bf16*)(ws + o);       o += 64 * Ns;  // 128N bf16

  // prep (input-only dependencies)
  transpose_both<<<(128 * 128 + 64 * 128 + 255) / 256, 256, 0, stream>>>(W2, Wt2, W1, Wt1);
  hipMemsetAsync(deg, 0, degPad * sizeof(int), stream);
  count_both_kernel<<<(E2 + E1 + 255) / 256, 256, 0, stream>>>(ei2, deg2, E2, ei1, deg1, E1);
  scan_partial_kernel<<<nb, 256, 0, stream>>>(deg, bsum);
  scan_apply_kernel<<<nb, 256, 0, stream>>>(deg, bsum, rowptr2, N2, N, E2);

  // ---- layer 2: 128 -> [2 heads x 64], concat ----
  gemm_att_kernel<128, 128, 32, 2, float>
      <<<(N + 31) / 32, 128, 0, stream>>>(x, Wt2, as2, ad2, h2, asrc2, adst2, N);
  fillp2_kernel<<<(E2 + 255) / 256, 256, 0, stream>>>(ei2, asrc2, adst2, rowptr2, eidx2, pcsr2, E2);
  gather2_kernel<<<(N + 3) / 4, 256, 0, stream>>>(h2, asrc2, adst2, rowptr2, eidx2, pcsr2, b2,
                                                  hin1, N);

  // ---- layer 1: 128 -> 64, single head ----
  gemm_att_kernel<128, 64, 32, 1, bf16>
      <<<(N + 31) / 32, 64, 0, stream>>>(hin1, Wt1, as1, ad1, h1, asrc1, adst1, N);
  fillp1_kernel<<<(E1 + 255) / 256, 256, 0, stream>>>(ei1, asrc1, adst1, rowptr1, eidx1, pcsr1, E1);
  gather1_kernel<<<(N + 3) / 4, 256, 0, stream>>>(h1, asrc1, adst1, rowptr1, eidx1, pcsr1, b1, out,
                                                  N);
}

// Round 5
// 480.086 us; speedup vs baseline: 4.6812x; 1.4857x over previous
//
#include <hip/hip_runtime.h>
#include <hip/hip_bf16.h>
#include <math.h>

#define LRELU_SLOPE 0.2f
#define EPS 1e-16f
#define BUCK_SHIFT 8
#define BUCK_NODES 256
#define MAXBUCK 512

typedef __hip_bfloat16 bf16;

__device__ inline float lrelu(float v) { return v > 0.f ? v : LRELU_SLOPE * v; }
__device__ inline float bflo(unsigned u) { return __uint_as_float(u << 16); }
__device__ inline float bfhi(unsigned u) { return __uint_as_float(u & 0xffff0000u); }

// ---------------- both W transposes in one launch ----------------
__global__ void transpose_both(const float* __restrict__ W2, float* __restrict__ Wt2,
                               const float* __restrict__ W1, float* __restrict__ Wt1) {
  int idx = blockIdx.x * blockDim.x + threadIdx.x;
  if (idx < 128 * 128) {
    int m = idx >> 7, k = idx & 127;
    Wt2[k * 128 + m] = W2[idx];
  } else {
    int i = idx - 128 * 128;
    if (i < 64 * 128) {
      int m = i >> 7, k = i & 127;
      Wt1[k * 64 + m] = W1[i];
    }
  }
}

// ---------------- bucket partition: edges -> per-bucket slabs of (s,d) ----------------
// Block-aggregated reservation: one global atomic per (block,bucket) instead of per edge.
template <int EPB>
__global__ __launch_bounds__(256) void partition_kernel(const int* __restrict__ ei, int E,
                                                        int* __restrict__ gcur,
                                                        int2* __restrict__ part, int cap,
                                                        int nbuck) {
  __shared__ int cnt[MAXBUCK];
  __shared__ int sbase[MAXBUCK];
  const int tid = threadIdx.x;
  for (int t = tid; t < nbuck; t += 256) cnt[t] = 0;
  __syncthreads();
  const int e0 = blockIdx.x * EPB;
  constexpr int KPT = EPB / 256;
  int sv[KPT], dv[KPT];
#pragma unroll
  for (int k = 0; k < KPT; k++) {
    int e = e0 + tid + k * 256;
    if (e < E) {
      sv[k] = ei[e];
      dv[k] = ei[E + e];
      atomicAdd(&cnt[dv[k] >> BUCK_SHIFT], 1);
    } else {
      dv[k] = -1;
    }
  }
  __syncthreads();
  for (int t = tid; t < nbuck; t += 256) {
    int c = cnt[t];
    if (c) sbase[t] = atomicAdd(&gcur[t], c);
    cnt[t] = 0;
  }
  __syncthreads();
#pragma unroll
  for (int k = 0; k < KPT; k++) {
    if (dv[k] >= 0) {
      int b = dv[k] >> BUCK_SHIFT;
      int pos = sbase[b] + atomicAdd(&cnt[b], 1);
      if (pos < cap) part[(size_t)b * cap + pos] = make_int2(sv[k], dv[k]);
    }
  }
}

// ---------------- per-bucket CSR build: LDS histogram+scan, no global atomics ----------------
// Writes rowbeg/rowend (slab-absolute), eidx (src), pcsr (softmax numerators).
template <int H>
__global__ __launch_bounds__(256) void csr_build_kernel(
    const int2* __restrict__ part, const int* __restrict__ gcur, int cap,
    const float* __restrict__ asrc, const float* __restrict__ adst, int* __restrict__ eidx,
    float* __restrict__ pcsr, int* __restrict__ rowbeg, int* __restrict__ rowend, int N) {
  extern __shared__ char smem[];
  int* s_s = (int*)smem;                                  // [cap]
  unsigned short* s_d8 = (unsigned short*)(s_s + cap);    // [cap]
  int* hist = (int*)(s_d8 + cap);                         // [256]
  int* escan = hist + 256;                                // [256]
  int* cur = escan + 256;                                 // [256]
  float* s_ad = (float*)(cur + 256);                      // [H*256]

  const int b = blockIdx.x;
  const int tid = threadIdx.x;
  const int nb0 = b << BUCK_SHIFT;
  const int nn = min(BUCK_NODES, N - nb0);
  const int cnt = min(gcur[b], cap);
  const int B = b * cap;

  hist[tid] = 0;
  cur[tid] = 0;
  for (int t = tid; t < nn * H; t += 256) s_ad[t] = adst[(size_t)nb0 * H + t];
  __syncthreads();
  for (int i = tid; i < cnt; i += 256) {
    int2 pr = part[(size_t)B + i];
    s_s[i] = pr.x;
    int d8 = pr.y & (BUCK_NODES - 1);
    s_d8[i] = (unsigned short)d8;
    atomicAdd(&hist[d8], 1);
  }
  __syncthreads();
  // Hillis-Steele inclusive scan of hist -> escan
  escan[tid] = hist[tid];
  __syncthreads();
  for (int off = 1; off < 256; off <<= 1) {
    int t = (tid >= off) ? escan[tid - off] : 0;
    __syncthreads();
    escan[tid] += t;
    __syncthreads();
  }
  if (tid < nn) {
    rowbeg[nb0 + tid] = B + escan[tid] - hist[tid];
    rowend[nb0 + tid] = B + escan[tid];
  }
  __syncthreads();
  for (int i = tid; i < cnt; i += 256) {
    int d8 = s_d8[i];
    int slot = B + (escan[d8] - hist[d8]) + atomicAdd(&cur[d8], 1);
    int s = s_s[i];
    eidx[slot] = s;
    if constexpr (H == 2) {
      float2 a = *(const float2*)&asrc[2 * (size_t)s];
      float2 ad = *(const float2*)&s_ad[2 * d8];
      float2 pv;
      pv.x = __expf(lrelu(a.x + ad.x));
      pv.y = __expf(lrelu(a.y + ad.y));
      *(float2*)&pcsr[2 * (size_t)slot] = pv;
    } else {
      pcsr[slot] = __expf(lrelu(asrc[s] + s_ad[d8]));
    }
  }
}

// ---------------- GEMM (h = x @ Wt) + fused att dot-products ----------------
template <int K, int M, int NPB, int H, typename Tin>
__global__ __launch_bounds__(M) void gemm_att_kernel(
    const Tin* __restrict__ x, const float* __restrict__ Wt, const float* __restrict__ atts,
    const float* __restrict__ attd, bf16* __restrict__ h, float* __restrict__ asrc,
    float* __restrict__ adst, int N) {
  __shared__ float xs[NPB * (K + 1)];  // staging uses stride K; epilogue uses stride M+1
  const int tid = threadIdx.x;
  const long long nbase = (long long)blockIdx.x * NPB;
  const bool full = (nbase + NPB) <= (long long)N;

  if constexpr (sizeof(Tin) == 4) {
    const float4* xv = (const float4*)(x + nbase * K);
    constexpr int CNT = NPB * K / 4;
    for (int i = tid; i < CNT; i += M) {
      float4 v = make_float4(0.f, 0.f, 0.f, 0.f);
      if (full || (nbase + (i * 4) / K) < N) v = xv[i];
      *(float4*)&xs[i * 4] = v;
    }
  } else {
    const uint4* xv = (const uint4*)((const unsigned short*)x + nbase * K);
    constexpr int CNT = NPB * K / 8;
    for (int i = tid; i < CNT; i += M) {
      uint4 v = make_uint4(0, 0, 0, 0);
      if (full || (nbase + (i * 8) / K) < N) v = xv[i];
      float* dst = &xs[i * 8];
      dst[0] = bflo(v.x); dst[1] = bfhi(v.x);
      dst[2] = bflo(v.y); dst[3] = bfhi(v.y);
      dst[4] = bflo(v.z); dst[5] = bfhi(v.z);
      dst[6] = bflo(v.w); dst[7] = bfhi(v.w);
    }
  }
  __syncthreads();

  float acc[NPB];
#pragma unroll
  for (int j = 0; j < NPB; j++) acc[j] = 0.f;
  for (int k0 = 0; k0 < K; k0 += 8) {
    float w[8];
#pragma unroll
    for (int kk = 0; kk < 8; kk++) w[kk] = Wt[(k0 + kk) * M + tid];
#pragma unroll
    for (int j = 0; j < NPB; j++) {
      const float4 xa = *(const float4*)&xs[j * K + k0];
      const float4 xb = *(const float4*)&xs[j * K + k0 + 4];
      acc[j] += xa.x * w[0] + xa.y * w[1] + xa.z * w[2] + xa.w * w[3] +
                xb.x * w[4] + xb.y * w[5] + xb.z * w[6] + xb.w * w[7];
    }
  }

#pragma unroll
  for (int j = 0; j < NPB; j++) {
    long long n = nbase + j;
    if (full || n < N) h[n * M + tid] = __float2bfloat16(acc[j]);
  }

  __syncthreads();
#pragma unroll
  for (int j = 0; j < NPB; j++) xs[j * (M + 1) + tid] = acc[j];
  __syncthreads();
  constexpr int TPN = M / NPB;
  constexpr int CPT = M / TPN;
  const int node = tid / TPN;
  const int part = tid % TPN;
  const long long n = nbase + node;
  if (full || n < N) {
    const int c0 = part * CPT;
    float ssum = 0.f, dsum = 0.f;
#pragma unroll
    for (int cc = 0; cc < CPT; cc++) {
      int c = c0 + cc;
      float hv = xs[node * (M + 1) + c];
      ssum += hv * atts[c];
      dsum += hv * attd[c];
    }
    ssum += __shfl_xor(ssum, 1);
    dsum += __shfl_xor(dsum, 1);
    if constexpr (TPN == 4) {
      if ((part & 1) == 0) {
        int head = part >> 1;
        asrc[n * H + head] = ssum;
        adst[n * H + head] = dsum;
      }
    } else {
      if (part == 0) {
        asrc[n] = ssum;
        adst[n] = dsum;
      }
    }
  }
}

// ---------------- gather, layer2 (H=2, C=64): one wave per dst node ----------------
__global__ void gather2_kernel(const bf16* __restrict__ h, const float* __restrict__ asrc,
                               const float* __restrict__ adst, const int* __restrict__ rowbeg,
                               const int* __restrict__ rowend, const int* __restrict__ eidx,
                               const float2* __restrict__ pcsr, const float* __restrict__ bias,
                               bf16* __restrict__ outp, int N) {
  long long gt = (long long)blockIdx.x * blockDim.x + threadIdx.x;
  int n = (int)(gt >> 6);
  int lane = threadIdx.x & 63;
  if (n >= N) return;
  int start = rowbeg[n];
  int end = rowend[n];
  const float2 as = *(const float2*)&asrc[2 * (size_t)n];
  const float2 ad = *(const float2*)&adst[2 * (size_t)n];
  float p0 = __expf(lrelu(as.x + ad.x));
  float p1 = __expf(lrelu(as.y + ad.y));
  float den0 = p0, den1 = p1;
  const bool h0 = lane < 32;
  float p = h0 ? p0 : p1;
  unsigned hv = *(const unsigned*)&h[(size_t)n * 128 + 2 * lane];
  float acc0 = p * bflo(hv), acc1 = p * bfhi(hv);
  int j = start;
  for (; j + 1 < end; j += 2) {
    int sA = eidx[j], sB = eidx[j + 1];
    float2 pA = pcsr[j], pB = pcsr[j + 1];
    unsigned hA = *(const unsigned*)&h[(size_t)sA * 128 + 2 * lane];
    unsigned hB = *(const unsigned*)&h[(size_t)sB * 128 + 2 * lane];
    den0 += pA.x + pB.x;
    den1 += pA.y + pB.y;
    float pa = h0 ? pA.x : pA.y;
    float pb = h0 ? pB.x : pB.y;
    acc0 += pa * bflo(hA) + pb * bflo(hB);
    acc1 += pa * bfhi(hA) + pb * bfhi(hB);
  }
  if (j < end) {
    int sA = eidx[j];
    float2 pA = pcsr[j];
    unsigned hA = *(const unsigned*)&h[(size_t)sA * 128 + 2 * lane];
    den0 += pA.x;
    den1 += pA.y;
    float pa = h0 ? pA.x : pA.y;
    acc0 += pa * bflo(hA);
    acc1 += pa * bfhi(hA);
  }
  float den = (h0 ? den0 : den1) + EPS;
  int c = 2 * lane;
  float v0 = acc0 / den + bias[c];
  float v1 = acc1 / den + bias[c + 1];
  v0 = v0 > 0.f ? v0 : expm1f(v0);
  v1 = v1 > 0.f ? v1 : expm1f(v1);
  __hip_bfloat162 o;
  o.x = __float2bfloat16(v0);
  o.y = __float2bfloat16(v1);
  *(__hip_bfloat162*)&outp[(size_t)n * 128 + c] = o;
}

// ---------------- gather, layer1 (H=1, C=64): one wave per dst node ----------------
__global__ void gather1_kernel(const bf16* __restrict__ h, const float* __restrict__ asrc,
                               const float* __restrict__ adst, const int* __restrict__ rowbeg,
                               const int* __restrict__ rowend, const int* __restrict__ eidx,
                               const float* __restrict__ pcsr, const float* __restrict__ bias,
                               float* __restrict__ outp, int N) {
  long long gt = (long long)blockIdx.x * blockDim.x + threadIdx.x;
  int n = (int)(gt >> 6);
  int lane = threadIdx.x & 63;
  if (n >= N) return;
  int start = rowbeg[n];
  int end = rowend[n];
  float p = __expf(lrelu(asrc[n] + adst[n]));
  float den = p;
  float acc = p * __bfloat162float(h[(size_t)n * 64 + lane]);
  int j = start;
  for (; j + 1 < end; j += 2) {
    int sA = eidx[j], sB = eidx[j + 1];
    float pA = pcsr[j], pB = pcsr[j + 1];
    float hA = __bfloat162float(h[(size_t)sA * 64 + lane]);
    float hB = __bfloat162float(h[(size_t)sB * 64 + lane]);
    den += pA + pB;
    acc += pA * hA + pB * hB;
  }
  if (j < end) {
    int sA = eidx[j];
    float pA = pcsr[j];
    den += pA;
    acc += pA * __bfloat162float(h[(size_t)sA * 64 + lane]);
  }
  float v = acc / (den + EPS) + bias[lane];
  outp[(size_t)n * 64 + lane] = v > 0.f ? v : expm1f(v);
}

extern "C" void kernel_launch(void* const* d_in, const int* in_sizes, int n_in,
                              void* d_out, int out_size, void* d_ws, size_t ws_size,
                              hipStream_t stream) {
  const float* x = (const float*)d_in[0];
  const int* ei1 = (const int*)d_in[1];
  const int* ei2 = (const int*)d_in[2];
  const float* W2 = (const float*)d_in[3];
  const float* as2 = (const float*)d_in[4];
  const float* ad2 = (const float*)d_in[5];
  const float* b2 = (const float*)d_in[6];
  const float* W1 = (const float*)d_in[7];
  const float* as1 = (const float*)d_in[8];
  const float* ad1 = (const float*)d_in[9];
  const float* b1 = (const float*)d_in[10];
  float* out = (float*)d_out;

  const int N = in_sizes[0] / 128;
  const int E1 = in_sizes[1] / 2;
  const int E2 = in_sizes[2] / 2;
  const int Emax = E1 > E2 ? E1 : E2;
  const size_t Ns = (size_t)N;

  const int nbuck = (N + BUCK_NODES - 1) / BUCK_NODES;  // 391 for N=100k (<= MAXBUCK)
  int lam = (Emax + nbuck - 1) / nbuck;
  int cap = lam + (lam >> 2) + 512;
  cap = (cap + 255) & ~(int)255;
  const size_t NC = (size_t)nbuck * cap;

  float* ws = (float*)d_ws;
  size_t o = 0;
  float* Wt2 = ws + o;    o += 16384;
  float* Wt1 = ws + o;    o += 8192;
  float* asrc2 = ws + o;  o += 2 * Ns;
  float* adst2 = ws + o;  o += 2 * Ns;
  float* asrc1 = ws + o;  o += Ns;
  float* adst1 = ws + o;  o += Ns;
  int* gcur2 = (int*)(ws + o);   o += (size_t)nbuck;
  int* gcur1 = (int*)(ws + o);   o += (size_t)nbuck;
  int* rowbeg2 = (int*)(ws + o); o += Ns;
  int* rowend2 = (int*)(ws + o); o += Ns;
  int* rowbeg1 = (int*)(ws + o); o += Ns;
  int* rowend1 = (int*)(ws + o); o += Ns;
  o = (o + 7) & ~(size_t)7;
  int2* part = (int2*)(ws + o);  o += 2 * NC;   // shared by both layers (sequenced)
  int* eidx = (int*)(ws + o);    o += NC;       // shared by both layers
  o = (o + 7) & ~(size_t)7;
  float* pcsr = ws + o;          o += 2 * NC;   // l2: float2[NC]; l1: float[NC]
  o = (o + 7) & ~(size_t)7;
  bf16* h2 = (bf16*)(ws + o);    o += 64 * Ns;  // 128N bf16; h1 aliases
  bf16* h1 = h2;
  bf16* hin1 = (bf16*)(ws + o);  o += 64 * Ns;  // 128N bf16

  const size_t smem2 = (size_t)cap * 6 + 3 * 256 * 4 + 2 * 256 * 4 + 64;
  const size_t smem1 = (size_t)cap * 6 + 3 * 256 * 4 + 1 * 256 * 4 + 64;

  // prep
  transpose_both<<<(128 * 128 + 64 * 128 + 255) / 256, 256, 0, stream>>>(W2, Wt2, W1, Wt1);
  hipMemsetAsync(gcur2, 0, 2 * (size_t)nbuck * sizeof(int), stream);

  // ---- layer 2: 128 -> [2 heads x 64], concat ----
  partition_kernel<4096><<<(E2 + 4095) / 4096, 256, 0, stream>>>(ei2, E2, gcur2, part, cap, nbuck);
  gemm_att_kernel<128, 128, 32, 2, float>
      <<<(N + 31) / 32, 128, 0, stream>>>(x, Wt2, as2, ad2, h2, asrc2, adst2, N);
  csr_build_kernel<2><<<nbuck, 256, smem2, stream>>>(part, gcur2, cap, asrc2, adst2, eidx, pcsr,
                                                     rowbeg2, rowend2, N);
  partition_kernel<4096><<<(E1 + 4095) / 4096, 256, 0, stream>>>(ei1, E1, gcur1, part, cap, nbuck);
  gather2_kernel<<<(N + 3) / 4, 256, 0, stream>>>(h2, asrc2, adst2, rowbeg2, rowend2, eidx,
                                                  (const float2*)pcsr, b2, hin1, N);

  // ---- layer 1: 128 -> 64, single head ----
  gemm_att_kernel<128, 64, 32, 1, bf16>
      <<<(N + 31) / 32, 64, 0, stream>>>(hin1, Wt1, as1, ad1, h1, asrc1, adst1, N);
  csr_build_kernel<1><<<nbuck, 256, smem1, stream>>>(part, gcur1, cap, asrc1, adst1, eidx, pcsr,
                                                     rowbeg1, rowend1, N);
  gather1_kernel<<<(N + 3) / 4, 256, 0, stream>>>(h1, asrc1, adst1, rowbeg1, rowend1, eidx, pcsr,
                                                  b1, out, N);
}

// Round 6
// 343.074 us; speedup vs baseline: 6.5507x; 1.3994x over previous
//
#include <hip/hip_runtime.h>
#include <hip/hip_bf16.h>
#include <math.h>

#define LRELU_SLOPE 0.2f
#define EPS 1e-16f
#define BUCK_SHIFT 8
#define BUCK_NODES 256
#define MAXBUCK 512

typedef __hip_bfloat16 bf16;
typedef __attribute__((ext_vector_type(8))) short bf16x8;
typedef __attribute__((ext_vector_type(4))) float f32x4;

__device__ inline float lrelu(float v) { return v > 0.f ? v : LRELU_SLOPE * v; }
__device__ inline float bflo(unsigned u) { return __uint_as_float(u << 16); }
__device__ inline float bfhi(unsigned u) { return __uint_as_float(u & 0xffff0000u); }
__device__ inline short f2bf(float f) {
  bf16 t = __float2bfloat16(f);
  return *reinterpret_cast<short*>(&t);
}

// ---------------- W f32 -> bf16 (row-major, no transpose: MFMA B-frag reads along k) ------
__global__ void convert_w(const float* __restrict__ W2, unsigned short* __restrict__ Wb2,
                          const float* __restrict__ W1, unsigned short* __restrict__ Wb1) {
  int idx = blockIdx.x * blockDim.x + threadIdx.x;
  if (idx < 16384) {
    Wb2[idx] = (unsigned short)f2bf(W2[idx]);
  } else {
    int i = idx - 16384;
    if (i < 8192) Wb1[i] = (unsigned short)f2bf(W1[i]);
  }
}

// ---------------- bucket partition: edges -> per-bucket slabs of (s,d) ----------------
template <int EPB>
__global__ __launch_bounds__(256) void partition_kernel(const int* __restrict__ ei, int E,
                                                        int* __restrict__ gcur,
                                                        int2* __restrict__ part, int cap,
                                                        int nbuck) {
  __shared__ int cnt[MAXBUCK];
  __shared__ int sbase[MAXBUCK];
  const int tid = threadIdx.x;
  for (int t = tid; t < nbuck; t += 256) cnt[t] = 0;
  __syncthreads();
  const int e0 = blockIdx.x * EPB;
  constexpr int KPT = EPB / 256;
  int sv[KPT], dv[KPT];
#pragma unroll
  for (int k = 0; k < KPT; k++) {
    int e = e0 + tid + k * 256;
    if (e < E) {
      sv[k] = ei[e];
      dv[k] = ei[E + e];
      atomicAdd(&cnt[dv[k] >> BUCK_SHIFT], 1);
    } else {
      dv[k] = -1;
    }
  }
  __syncthreads();
  for (int t = tid; t < nbuck; t += 256) {
    int c = cnt[t];
    if (c) sbase[t] = atomicAdd(&gcur[t], c);
    cnt[t] = 0;
  }
  __syncthreads();
#pragma unroll
  for (int k = 0; k < KPT; k++) {
    if (dv[k] >= 0) {
      int b = dv[k] >> BUCK_SHIFT;
      int pos = sbase[b] + atomicAdd(&cnt[b], 1);
      if (pos < cap) part[(size_t)b * cap + pos] = make_int2(sv[k], dv[k]);
    }
  }
}

// ---------------- per-bucket CSR build: LDS histogram+scan, no global atomics ----------------
template <int H>
__global__ __launch_bounds__(256) void csr_build_kernel(
    const int2* __restrict__ part, const int* __restrict__ gcur, int cap,
    const float* __restrict__ asrc, const float* __restrict__ adst, int* __restrict__ eidx,
    float* __restrict__ pcsr, int* __restrict__ rowbeg, int* __restrict__ rowend, int N) {
  extern __shared__ char smem[];
  int* s_s = (int*)smem;                                  // [cap]
  unsigned short* s_d8 = (unsigned short*)(s_s + cap);    // [cap]
  int* hist = (int*)(s_d8 + cap);                         // [256]
  int* escan = hist + 256;                                // [256]
  int* cur = escan + 256;                                 // [256]
  float* s_ad = (float*)(cur + 256);                      // [H*256]

  const int b = blockIdx.x;
  const int tid = threadIdx.x;
  const int nb0 = b << BUCK_SHIFT;
  const int nn = min(BUCK_NODES, N - nb0);
  const int cnt = min(gcur[b], cap);
  const int B = b * cap;

  hist[tid] = 0;
  cur[tid] = 0;
  for (int t = tid; t < nn * H; t += 256) s_ad[t] = adst[(size_t)nb0 * H + t];
  __syncthreads();
  for (int i = tid; i < cnt; i += 256) {
    int2 pr = part[(size_t)B + i];
    s_s[i] = pr.x;
    int d8 = pr.y & (BUCK_NODES - 1);
    s_d8[i] = (unsigned short)d8;
    atomicAdd(&hist[d8], 1);
  }
  __syncthreads();
  escan[tid] = hist[tid];
  __syncthreads();
  for (int off = 1; off < 256; off <<= 1) {
    int t = (tid >= off) ? escan[tid - off] : 0;
    __syncthreads();
    escan[tid] += t;
    __syncthreads();
  }
  if (tid < nn) {
    rowbeg[nb0 + tid] = B + escan[tid] - hist[tid];
    rowend[nb0 + tid] = B + escan[tid];
  }
  __syncthreads();
  for (int i = tid; i < cnt; i += 256) {
    int d8 = s_d8[i];
    int slot = B + (escan[d8] - hist[d8]) + atomicAdd(&cur[d8], 1);
    int s = s_s[i];
    eidx[slot] = s;
    if constexpr (H == 2) {
      float2 a = *(const float2*)&asrc[2 * (size_t)s];
      float2 ad = *(const float2*)&s_ad[2 * d8];
      float2 pv;
      pv.x = __expf(lrelu(a.x + ad.x));
      pv.y = __expf(lrelu(a.y + ad.y));
      *(float2*)&pcsr[2 * (size_t)slot] = pv;
    } else {
      pcsr[slot] = __expf(lrelu(asrc[s] + s_ad[d8]));
    }
  }
}

// ---------------- MFMA GEMM (h = x @ W^T, bf16) + fused att dot-products ----------------
// Block = 256 thr = 4 waves; wave = 16 node-rows x M cols. K = 128.
// A-frag: row = lane&15, k = (lane>>4)*8 + j. B-frag: col = lane&15, same k mapping
// (identical k->position permutation on both sides cancels). C/D: col = lane&15,
// row = (lane>>4)*4 + reg  [m89-verified].
// SPLIT: f32 input fed as exact hi+lo bf16 pair (2 MFMAs) to kill input-rounding error.
template <int M, int H, bool SPLIT, typename Tin>
__global__ __launch_bounds__(256) void gemm_att_mfma(
    const Tin* __restrict__ x, const unsigned short* __restrict__ Wb,
    const float* __restrict__ atts, const float* __restrict__ attd, bf16* __restrict__ h,
    float* __restrict__ asrc, float* __restrict__ adst, int N) {
  constexpr int K = 128;
  constexpr int NF = M / 16;
  const int wid = threadIdx.x >> 6;
  const int lane = threadIdx.x & 63;
  const int r0 = blockIdx.x * 64 + wid * 16;
  if (r0 >= N) return;
  const int colb = lane & 15;
  const int kgrp = lane >> 4;
  const size_t arow = (size_t)min(r0 + colb, N - 1);

  f32x4 acc[NF];
#pragma unroll
  for (int f = 0; f < NF; f++) acc[f] = (f32x4){0.f, 0.f, 0.f, 0.f};

#pragma unroll
  for (int k0 = 0; k0 < K; k0 += 32) {
    const int kb = k0 + kgrp * 8;
    bf16x8 ahi, alo;
    if constexpr (SPLIT) {
      const float* xp = (const float*)x + arow * K + kb;
      float4 l0 = *(const float4*)xp;
      float4 l1 = *(const float4*)(xp + 4);
      float xv[8] = {l0.x, l0.y, l0.z, l0.w, l1.x, l1.y, l1.z, l1.w};
#pragma unroll
      for (int j = 0; j < 8; j++) {
        short hb = f2bf(xv[j]);
        ahi[j] = hb;
        float hf = __uint_as_float(((unsigned)(unsigned short)hb) << 16);
        alo[j] = f2bf(xv[j] - hf);
      }
    } else {
      ahi = *(const bf16x8*)((const unsigned short*)x + arow * K + kb);
    }
#pragma unroll
    for (int f = 0; f < NF; f++) {
      bf16x8 b = *(const bf16x8*)(Wb + (size_t)(f * 16 + colb) * K + kb);
      if constexpr (SPLIT)
        acc[f] = __builtin_amdgcn_mfma_f32_16x16x32_bf16(alo, b, acc[f], 0, 0, 0);
      acc[f] = __builtin_amdgcn_mfma_f32_16x16x32_bf16(ahi, b, acc[f], 0, 0, 0);
    }
  }

  // epilogue: store h (bf16) + att dot-products (reduce across the 16 lanes of a row-group)
#pragma unroll
  for (int r = 0; r < 4; r++) {
    const int row = r0 + kgrp * 4 + r;
    const bool ok = row < N;
    float s0 = 0.f, d0 = 0.f, s1 = 0.f, d1 = 0.f;
#pragma unroll
    for (int f = 0; f < NF; f++) {
      float v = acc[f][r];
      int c = f * 16 + colb;
      if (ok) h[(size_t)row * M + c] = __float2bfloat16(v);
      float av = atts[c], dv = attd[c];
      if (H == 2 && f >= NF / 2) {
        s1 += v * av;
        d1 += v * dv;
      } else {
        s0 += v * av;
        d0 += v * dv;
      }
    }
#pragma unroll
    for (int off = 1; off < 16; off <<= 1) {
      s0 += __shfl_xor(s0, off);
      d0 += __shfl_xor(d0, off);
      if (H == 2) {
        s1 += __shfl_xor(s1, off);
        d1 += __shfl_xor(d1, off);
      }
    }
    if (ok && colb == 0) {
      if (H == 2) {
        asrc[2 * (size_t)row] = s0;
        asrc[2 * (size_t)row + 1] = s1;
        adst[2 * (size_t)row] = d0;
        adst[2 * (size_t)row + 1] = d1;
      } else {
        asrc[row] = s0;
        adst[row] = d0;
      }
    }
  }
}

// ---------------- gather, layer2 (H=2, C=64): one wave per dst node, unroll x4 ----------------
__global__ void gather2_kernel(const bf16* __restrict__ h, const float* __restrict__ asrc,
                               const float* __restrict__ adst, const int* __restrict__ rowbeg,
                               const int* __restrict__ rowend, const int* __restrict__ eidx,
                               const float2* __restrict__ pcsr, const float* __restrict__ bias,
                               bf16* __restrict__ outp, int N) {
  long long gt = (long long)blockIdx.x * blockDim.x + threadIdx.x;
  int n = (int)(gt >> 6);
  int lane = threadIdx.x & 63;
  if (n >= N) return;
  int start = rowbeg[n];
  int end = rowend[n];
  const float2 as = *(const float2*)&asrc[2 * (size_t)n];
  const float2 ad = *(const float2*)&adst[2 * (size_t)n];
  float p0 = __expf(lrelu(as.x + ad.x));
  float p1 = __expf(lrelu(as.y + ad.y));
  float den0 = p0, den1 = p1;
  const bool h0 = lane < 32;
  float p = h0 ? p0 : p1;
  unsigned hv = *(const unsigned*)&h[(size_t)n * 128 + 2 * lane];
  float acc0 = p * bflo(hv), acc1 = p * bfhi(hv);
  int j = start;
  for (; j + 3 < end; j += 4) {
    int sA = eidx[j], sB = eidx[j + 1], sC = eidx[j + 2], sD = eidx[j + 3];
    float2 pA = pcsr[j], pB = pcsr[j + 1], pC = pcsr[j + 2], pD = pcsr[j + 3];
    unsigned hA = *(const unsigned*)&h[(size_t)sA * 128 + 2 * lane];
    unsigned hB = *(const unsigned*)&h[(size_t)sB * 128 + 2 * lane];
    unsigned hC = *(const unsigned*)&h[(size_t)sC * 128 + 2 * lane];
    unsigned hD = *(const unsigned*)&h[(size_t)sD * 128 + 2 * lane];
    den0 += (pA.x + pB.x) + (pC.x + pD.x);
    den1 += (pA.y + pB.y) + (pC.y + pD.y);
    float pa = h0 ? pA.x : pA.y;
    float pb = h0 ? pB.x : pB.y;
    float pc = h0 ? pC.x : pC.y;
    float pd = h0 ? pD.x : pD.y;
    acc0 += (pa * bflo(hA) + pb * bflo(hB)) + (pc * bflo(hC) + pd * bflo(hD));
    acc1 += (pa * bfhi(hA) + pb * bfhi(hB)) + (pc * bfhi(hC) + pd * bfhi(hD));
  }
  for (; j < end; j++) {
    int sA = eidx[j];
    float2 pA = pcsr[j];
    unsigned hA = *(const unsigned*)&h[(size_t)sA * 128 + 2 * lane];
    den0 += pA.x;
    den1 += pA.y;
    float pa = h0 ? pA.x : pA.y;
    acc0 += pa * bflo(hA);
    acc1 += pa * bfhi(hA);
  }
  float den = (h0 ? den0 : den1) + EPS;
  int c = 2 * lane;
  float v0 = acc0 / den + bias[c];
  float v1 = acc1 / den + bias[c + 1];
  v0 = v0 > 0.f ? v0 : expm1f(v0);
  v1 = v1 > 0.f ? v1 : expm1f(v1);
  __hip_bfloat162 o;
  o.x = __float2bfloat16(v0);
  o.y = __float2bfloat16(v1);
  *(__hip_bfloat162*)&outp[(size_t)n * 128 + c] = o;
}

// ---------------- gather, layer1 (H=1, C=64): one wave per dst node, unroll x4 ----------------
__global__ void gather1_kernel(const bf16* __restrict__ h, const float* __restrict__ asrc,
                               const float* __restrict__ adst, const int* __restrict__ rowbeg,
                               const int* __restrict__ rowend, const int* __restrict__ eidx,
                               const float* __restrict__ pcsr, const float* __restrict__ bias,
                               float* __restrict__ outp, int N) {
  long long gt = (long long)blockIdx.x * blockDim.x + threadIdx.x;
  int n = (int)(gt >> 6);
  int lane = threadIdx.x & 63;
  if (n >= N) return;
  int start = rowbeg[n];
  int end = rowend[n];
  float p = __expf(lrelu(asrc[n] + adst[n]));
  float den = p;
  float acc = p * __bfloat162float(h[(size_t)n * 64 + lane]);
  int j = start;
  for (; j + 3 < end; j += 4) {
    int sA = eidx[j], sB = eidx[j + 1], sC = eidx[j + 2], sD = eidx[j + 3];
    float pA = pcsr[j], pB = pcsr[j + 1], pC = pcsr[j + 2], pD = pcsr[j + 3];
    float hA = __bfloat162float(h[(size_t)sA * 64 + lane]);
    float hB = __bfloat162float(h[(size_t)sB * 64 + lane]);
    float hC = __bfloat162float(h[(size_t)sC * 64 + lane]);
    float hD = __bfloat162float(h[(size_t)sD * 64 + lane]);
    den += (pA + pB) + (pC + pD);
    acc += (pA * hA + pB * hB) + (pC * hC + pD * hD);
  }
  for (; j < end; j++) {
    int sA = eidx[j];
    float pA = pcsr[j];
    den += pA;
    acc += pA * __bfloat162float(h[(size_t)sA * 64 + lane]);
  }
  float v = acc / (den + EPS) + bias[lane];
  outp[(size_t)n * 64 + lane] = v > 0.f ? v : expm1f(v);
}

extern "C" void kernel_launch(void* const* d_in, const int* in_sizes, int n_in,
                              void* d_out, int out_size, void* d_ws, size_t ws_size,
                              hipStream_t stream) {
  const float* x = (const float*)d_in[0];
  const int* ei1 = (const int*)d_in[1];
  const int* ei2 = (const int*)d_in[2];
  const float* W2 = (const float*)d_in[3];
  const float* as2 = (const float*)d_in[4];
  const float* ad2 = (const float*)d_in[5];
  const float* b2 = (const float*)d_in[6];
  const float* W1 = (const float*)d_in[7];
  const float* as1 = (const float*)d_in[8];
  const float* ad1 = (const float*)d_in[9];
  const float* b1 = (const float*)d_in[10];
  float* out = (float*)d_out;

  const int N = in_sizes[0] / 128;
  const int E1 = in_sizes[1] / 2;
  const int E2 = in_sizes[2] / 2;
  const int Emax = E1 > E2 ? E1 : E2;
  const size_t Ns = (size_t)N;

  const int nbuck = (N + BUCK_NODES - 1) / BUCK_NODES;  // 391 for N=100k (<= MAXBUCK)
  int lam = (Emax + nbuck - 1) / nbuck;
  int cap = lam + (lam >> 2) + 512;
  cap = (cap + 255) & ~(int)255;
  const size_t NC = (size_t)nbuck * cap;

  float* ws = (float*)d_ws;
  size_t o = 0;
  unsigned short* Wb2 = (unsigned short*)(ws + o); o += 8192;   // 16384 bf16
  unsigned short* Wb1 = (unsigned short*)(ws + o); o += 4096;   // 8192 bf16
  float* asrc2 = ws + o;  o += 2 * Ns;
  float* adst2 = ws + o;  o += 2 * Ns;
  float* asrc1 = ws + o;  o += Ns;
  float* adst1 = ws + o;  o += Ns;
  int* gcur2 = (int*)(ws + o);   o += (size_t)nbuck;
  int* gcur1 = (int*)(ws + o);   o += (size_t)nbuck;
  int* rowbeg2 = (int*)(ws + o); o += Ns;
  int* rowend2 = (int*)(ws + o); o += Ns;
  int* rowbeg1 = (int*)(ws + o); o += Ns;
  int* rowend1 = (int*)(ws + o); o += Ns;
  o = (o + 7) & ~(size_t)7;
  int2* part = (int2*)(ws + o);  o += 2 * NC;   // shared by both layers (sequenced)
  int* eidx = (int*)(ws + o);    o += NC;       // shared by both layers
  o = (o + 7) & ~(size_t)7;
  float* pcsr = ws + o;          o += 2 * NC;   // l2: float2[NC]; l1: float[NC]
  o = (o + 7) & ~(size_t)7;
  bf16* h2 = (bf16*)(ws + o);    o += 64 * Ns;  // 128N bf16; h1 aliases
  bf16* h1 = h2;
  bf16* hin1 = (bf16*)(ws + o);  o += 64 * Ns;  // 128N bf16

  const size_t smem2 = (size_t)cap * 6 + 3 * 256 * 4 + 2 * 256 * 4 + 64;
  const size_t smem1 = (size_t)cap * 6 + 3 * 256 * 4 + 1 * 256 * 4 + 64;

  // prep
  convert_w<<<(16384 + 8192 + 255) / 256, 256, 0, stream>>>(W2, Wb2, W1, Wb1);
  hipMemsetAsync(gcur2, 0, 2 * (size_t)nbuck * sizeof(int), stream);

  // ---- layer 2: 128 -> [2 heads x 64], concat ----
  partition_kernel<4096><<<(E2 + 4095) / 4096, 256, 0, stream>>>(ei2, E2, gcur2, part, cap, nbuck);
  gemm_att_mfma<128, 2, true, float>
      <<<(N + 63) / 64, 256, 0, stream>>>(x, Wb2, as2, ad2, h2, asrc2, adst2, N);
  csr_build_kernel<2><<<nbuck, 256, smem2, stream>>>(part, gcur2, cap, asrc2, adst2, eidx, pcsr,
                                                     rowbeg2, rowend2, N);
  partition_kernel<4096><<<(E1 + 4095) / 4096, 256, 0, stream>>>(ei1, E1, gcur1, part, cap, nbuck);
  gather2_kernel<<<(N + 3) / 4, 256, 0, stream>>>(h2, asrc2, adst2, rowbeg2, rowend2, eidx,
                                                  (const float2*)pcsr, b2, hin1, N);

  // ---- layer 1: 128 -> 64, single head ----
  gemm_att_mfma<64, 1, false, bf16>
      <<<(N + 63) / 64, 256, 0, stream>>>(hin1, Wb1, as1, ad1, h1, asrc1, adst1, N);
  csr_build_kernel<1><<<nbuck, 256, smem1, stream>>>(part, gcur1, cap, asrc1, adst1, eidx, pcsr,
                                                     rowbeg1, rowend1, N);
  gather1_kernel<<<(N + 3) / 4, 256, 0, stream>>>(h1, asrc1, adst1, rowbeg1, rowend1, eidx, pcsr,
                                                  b1, out, N);
}

// Round 7
// 324.358 us; speedup vs baseline: 6.9287x; 1.0577x over previous
//
#include <hip/hip_runtime.h>
#include <hip/hip_bf16.h>
#include <math.h>

#define LRELU_SLOPE 0.2f
#define EPS 1e-16f
#define BUCK_SHIFT 8
#define BUCK_NODES 256
#define MAXBUCK 512

typedef __hip_bfloat16 bf16;
typedef __attribute__((ext_vector_type(8))) short bf16x8;
typedef __attribute__((ext_vector_type(4))) float f32x4;

__device__ inline float lrelu(float v) { return v > 0.f ? v : LRELU_SLOPE * v; }
__device__ inline float bflo(unsigned u) { return __uint_as_float(u << 16); }
__device__ inline float bfhi(unsigned u) { return __uint_as_float(u & 0xffff0000u); }
__device__ inline short f2bf(float f) {
  bf16 t = __float2bfloat16(f);
  return *reinterpret_cast<short*>(&t);
}

// ---------------- W f32 -> bf16 (row-major; MFMA B-frag reads along k) ----------------
__global__ void convert_w(const float* __restrict__ W2, unsigned short* __restrict__ Wb2,
                          const float* __restrict__ W1, unsigned short* __restrict__ Wb1) {
  int idx = blockIdx.x * blockDim.x + threadIdx.x;
  if (idx < 16384) {
    Wb2[idx] = (unsigned short)f2bf(W2[idx]);
  } else {
    int i = idx - 16384;
    if (i < 8192) Wb1[i] = (unsigned short)f2bf(W1[i]);
  }
}

// ---------------- bucket partition: edges -> per-bucket slabs of packed (s<<8|d8) ---------
template <int EPB>
__global__ __launch_bounds__(256) void partition_kernel(const int* __restrict__ ei, int E,
                                                        int* __restrict__ gcur,
                                                        int* __restrict__ part, int cap,
                                                        int nbuck) {
  __shared__ int cnt[MAXBUCK];
  __shared__ int sbase[MAXBUCK];
  const int tid = threadIdx.x;
  for (int t = tid; t < nbuck; t += 256) cnt[t] = 0;
  __syncthreads();
  const int e0 = blockIdx.x * EPB;
  constexpr int KPT = EPB / 256;
  int sv[KPT], dv[KPT];
#pragma unroll
  for (int k = 0; k < KPT; k++) {
    int e = e0 + tid + k * 256;
    if (e < E) {
      sv[k] = ei[e];
      dv[k] = ei[E + e];
      atomicAdd(&cnt[dv[k] >> BUCK_SHIFT], 1);
    } else {
      dv[k] = -1;
    }
  }
  __syncthreads();
  for (int t = tid; t < nbuck; t += 256) {
    int c = cnt[t];
    if (c) sbase[t] = atomicAdd(&gcur[t], c);
    cnt[t] = 0;
  }
  __syncthreads();
#pragma unroll
  for (int k = 0; k < KPT; k++) {
    if (dv[k] >= 0) {
      int b = dv[k] >> BUCK_SHIFT;
      int pos = sbase[b] + atomicAdd(&cnt[b], 1);
      if (pos < cap) part[(size_t)b * cap + pos] = (sv[k] << 8) | (dv[k] & (BUCK_NODES - 1));
    }
  }
}

// ---------------- per-bucket CSR build with pad-to-8 rows, no global atomics ----------------
template <int H>
__global__ __launch_bounds__(256) void csr_build_kernel(
    const int* __restrict__ part, const int* __restrict__ gcur, int cap,
    const float* __restrict__ asrc, const float* __restrict__ adst, int* __restrict__ eidx,
    float* __restrict__ pcsr, int* __restrict__ rowbeg, int* __restrict__ rowend, int N) {
  extern __shared__ char smem[];
  int* s_sd = (int*)smem;              // [cap] packed (s<<8|d8)
  int* hist = (int*)(s_sd + cap);      // [256]
  int* histp = hist + 256;             // [256] padded counts
  int* escanp = histp + 256;           // [256] inclusive scan of histp
  int* cur = escanp + 256;             // [256]
  float* s_ad = (float*)(cur + 256);   // [H*256]

  const int b = blockIdx.x;
  const int tid = threadIdx.x;
  const int nb0 = b << BUCK_SHIFT;
  const int nn = min(BUCK_NODES, N - nb0);
  const int cnt = min(gcur[b], cap - 7 * BUCK_NODES);  // room for worst-case padding
  const int B = b * cap;

  hist[tid] = 0;
  cur[tid] = 0;
  for (int t = tid; t < nn * H; t += 256) s_ad[t] = adst[(size_t)nb0 * H + t];
  __syncthreads();
  for (int i = tid; i < cnt; i += 256) {
    int pr = part[(size_t)B + i];
    s_sd[i] = pr;
    atomicAdd(&hist[pr & (BUCK_NODES - 1)], 1);
  }
  __syncthreads();
  int hp = (hist[tid] + 7) & ~7;
  histp[tid] = hp;
  escanp[tid] = hp;
  __syncthreads();
  for (int off = 1; off < 256; off <<= 1) {
    int t = (tid >= off) ? escanp[tid - off] : 0;
    __syncthreads();
    escanp[tid] += t;
    __syncthreads();
  }
  if (tid < nn) {
    rowbeg[nb0 + tid] = B + escanp[tid] - histp[tid];
    rowend[nb0 + tid] = B + escanp[tid];
  }
  __syncthreads();
  // scatter real edges
  for (int i = tid; i < cnt; i += 256) {
    int pr = s_sd[i];
    int d8 = pr & (BUCK_NODES - 1);
    int s = pr >> 8;
    int slot = B + (escanp[d8] - histp[d8]) + atomicAdd(&cur[d8], 1);
    eidx[slot] = s;
    if constexpr (H == 2) {
      float2 a = *(const float2*)&asrc[2 * (size_t)s];
      float2 ad = *(const float2*)&s_ad[2 * d8];
      float2 pv;
      pv.x = __expf(lrelu(a.x + ad.x));
      pv.y = __expf(lrelu(a.y + ad.y));
      *(float2*)&pcsr[2 * (size_t)slot] = pv;
    } else {
      pcsr[slot] = __expf(lrelu(asrc[s] + s_ad[d8]));
    }
  }
  // pad slots: src = dst node (valid row), p = 0 -> contributes nothing
  if (tid < nn) {
    int base = B + escanp[tid] - histp[tid];
    for (int k = hist[tid]; k < histp[tid]; k++) {
      eidx[base + k] = nb0 + tid;
      if constexpr (H == 2) {
        *(float2*)&pcsr[2 * (size_t)(base + k)] = make_float2(0.f, 0.f);
      } else {
        pcsr[base + k] = 0.f;
      }
    }
  }
}

// ---------------- MFMA GEMM (h = x @ W^T, bf16) + fused att dot-products ----------------
template <int M, int H, bool SPLIT, typename Tin>
__global__ __launch_bounds__(256) void gemm_att_mfma(
    const Tin* __restrict__ x, const unsigned short* __restrict__ Wb,
    const float* __restrict__ atts, const float* __restrict__ attd, bf16* __restrict__ h,
    float* __restrict__ asrc, float* __restrict__ adst, int N) {
  constexpr int K = 128;
  constexpr int NF = M / 16;
  const int wid = threadIdx.x >> 6;
  const int lane = threadIdx.x & 63;
  const int r0 = blockIdx.x * 64 + wid * 16;
  if (r0 >= N) return;
  const int colb = lane & 15;
  const int kgrp = lane >> 4;
  const size_t arow = (size_t)min(r0 + colb, N - 1);

  f32x4 acc[NF];
#pragma unroll
  for (int f = 0; f < NF; f++) acc[f] = (f32x4){0.f, 0.f, 0.f, 0.f};

#pragma unroll
  for (int k0 = 0; k0 < K; k0 += 32) {
    const int kb = k0 + kgrp * 8;
    bf16x8 ahi, alo;
    if constexpr (SPLIT) {
      const float* xp = (const float*)x + arow * K + kb;
      float4 l0 = *(const float4*)xp;
      float4 l1 = *(const float4*)(xp + 4);
      float xv[8] = {l0.x, l0.y, l0.z, l0.w, l1.x, l1.y, l1.z, l1.w};
#pragma unroll
      for (int j = 0; j < 8; j++) {
        short hb = f2bf(xv[j]);
        ahi[j] = hb;
        float hf = __uint_as_float(((unsigned)(unsigned short)hb) << 16);
        alo[j] = f2bf(xv[j] - hf);
      }
    } else {
      ahi = *(const bf16x8*)((const unsigned short*)x + arow * K + kb);
    }
#pragma unroll
    for (int f = 0; f < NF; f++) {
      bf16x8 b = *(const bf16x8*)(Wb + (size_t)(f * 16 + colb) * K + kb);
      if constexpr (SPLIT)
        acc[f] = __builtin_amdgcn_mfma_f32_16x16x32_bf16(alo, b, acc[f], 0, 0, 0);
      acc[f] = __builtin_amdgcn_mfma_f32_16x16x32_bf16(ahi, b, acc[f], 0, 0, 0);
    }
  }

#pragma unroll
  for (int r = 0; r < 4; r++) {
    const int row = r0 + kgrp * 4 + r;
    const bool ok = row < N;
    float s0 = 0.f, d0 = 0.f, s1 = 0.f, d1 = 0.f;
#pragma unroll
    for (int f = 0; f < NF; f++) {
      float v = acc[f][r];
      int c = f * 16 + colb;
      if (ok) h[(size_t)row * M + c] = __float2bfloat16(v);
      float av = atts[c], dv = attd[c];
      if (H == 2 && f >= NF / 2) {
        s1 += v * av;
        d1 += v * dv;
      } else {
        s0 += v * av;
        d0 += v * dv;
      }
    }
#pragma unroll
    for (int off = 1; off < 16; off <<= 1) {
      s0 += __shfl_xor(s0, off);
      d0 += __shfl_xor(d0, off);
      if (H == 2) {
        s1 += __shfl_xor(s1, off);
        d1 += __shfl_xor(d1, off);
      }
    }
    if (ok && colb == 0) {
      if (H == 2) {
        asrc[2 * (size_t)row] = s0;
        asrc[2 * (size_t)row + 1] = s1;
        adst[2 * (size_t)row] = d0;
        adst[2 * (size_t)row + 1] = d1;
      } else {
        asrc[row] = s0;
        adst[row] = d0;
      }
    }
  }
}

// ---------------- gather, layer2: one wave per dst node, padded x8, no tail ----------------
__global__ void gather2_kernel(const bf16* __restrict__ h, const float* __restrict__ asrc,
                               const float* __restrict__ adst, const int* __restrict__ rowbeg,
                               const int* __restrict__ rowend, const int* __restrict__ eidx,
                               const float* __restrict__ pcsr, const float* __restrict__ bias,
                               bf16* __restrict__ outp, int N) {
  long long gt = (long long)blockIdx.x * blockDim.x + threadIdx.x;
  int n = (int)(gt >> 6);
  int lane = threadIdx.x & 63;
  if (n >= N) return;
  int start = rowbeg[n];
  int end = rowend[n];
  const float2 as = *(const float2*)&asrc[2 * (size_t)n];
  const float2 ad = *(const float2*)&adst[2 * (size_t)n];
  float p0 = __expf(lrelu(as.x + ad.x));
  float p1 = __expf(lrelu(as.y + ad.y));
  float den0 = p0, den1 = p1;
  const bool h0 = lane < 32;
  float p = h0 ? p0 : p1;
  unsigned hv = *(const unsigned*)&h[(size_t)n * 128 + 2 * lane];
  float acc0 = p * bflo(hv), acc1 = p * bfhi(hv);
  for (int j = start; j < end; j += 8) {
    int4 ia = *(const int4*)&eidx[j];
    int4 ib = *(const int4*)&eidx[j + 4];
    float4 q0 = *(const float4*)&pcsr[2 * (size_t)j];
    float4 q1 = *(const float4*)&pcsr[2 * (size_t)j + 4];
    float4 q2 = *(const float4*)&pcsr[2 * (size_t)j + 8];
    float4 q3 = *(const float4*)&pcsr[2 * (size_t)j + 12];
    unsigned hA = *(const unsigned*)&h[(size_t)ia.x * 128 + 2 * lane];
    unsigned hB = *(const unsigned*)&h[(size_t)ia.y * 128 + 2 * lane];
    unsigned hC = *(const unsigned*)&h[(size_t)ia.z * 128 + 2 * lane];
    unsigned hD = *(const unsigned*)&h[(size_t)ia.w * 128 + 2 * lane];
    unsigned hE = *(const unsigned*)&h[(size_t)ib.x * 128 + 2 * lane];
    unsigned hF = *(const unsigned*)&h[(size_t)ib.y * 128 + 2 * lane];
    unsigned hG = *(const unsigned*)&h[(size_t)ib.z * 128 + 2 * lane];
    unsigned hH = *(const unsigned*)&h[(size_t)ib.w * 128 + 2 * lane];
    den0 += (q0.x + q0.z) + (q1.x + q1.z) + (q2.x + q2.z) + (q3.x + q3.z);
    den1 += (q0.y + q0.w) + (q1.y + q1.w) + (q2.y + q2.w) + (q3.y + q3.w);
    float pa = h0 ? q0.x : q0.y;
    float pb = h0 ? q0.z : q0.w;
    float pc = h0 ? q1.x : q1.y;
    float pd = h0 ? q1.z : q1.w;
    float pe = h0 ? q2.x : q2.y;
    float pf = h0 ? q2.z : q2.w;
    float pg = h0 ? q3.x : q3.y;
    float ph = h0 ? q3.z : q3.w;
    acc0 += (pa * bflo(hA) + pb * bflo(hB)) + (pc * bflo(hC) + pd * bflo(hD)) +
            (pe * bflo(hE) + pf * bflo(hF)) + (pg * bflo(hG) + ph * bflo(hH));
    acc1 += (pa * bfhi(hA) + pb * bfhi(hB)) + (pc * bfhi(hC) + pd * bfhi(hD)) +
            (pe * bfhi(hE) + pf * bfhi(hF)) + (pg * bfhi(hG) + ph * bfhi(hH));
  }
  float den = (h0 ? den0 : den1) + EPS;
  int c = 2 * lane;
  float v0 = acc0 / den + bias[c];
  float v1 = acc1 / den + bias[c + 1];
  v0 = v0 > 0.f ? v0 : expm1f(v0);
  v1 = v1 > 0.f ? v1 : expm1f(v1);
  __hip_bfloat162 o;
  o.x = __float2bfloat16(v0);
  o.y = __float2bfloat16(v1);
  *(__hip_bfloat162*)&outp[(size_t)n * 128 + c] = o;
}

// ---------------- gather, layer1: half-wave per edge-quad (8 rows in flight) ----------------
__global__ void gather1_kernel(const bf16* __restrict__ h, const float* __restrict__ asrc,
                               const float* __restrict__ adst, const int* __restrict__ rowbeg,
                               const int* __restrict__ rowend, const int* __restrict__ eidx,
                               const float* __restrict__ pcsr, const float* __restrict__ bias,
                               float* __restrict__ outp, int N) {
  long long gt = (long long)blockIdx.x * blockDim.x + threadIdx.x;
  int n = (int)(gt >> 6);
  int lane = threadIdx.x & 63;
  if (n >= N) return;
  const int half = lane >> 5;
  const int c = lane & 31;
  int start = rowbeg[n];
  int end = rowend[n];
  float pself = __expf(lrelu(asrc[n] + adst[n]));
  unsigned hv = *(const unsigned*)&h[(size_t)n * 64 + 2 * c];
  float g = half ? 0.f : pself;  // self-loop counted once (half 0)
  float den = g;
  float acc0 = g * bflo(hv), acc1 = g * bfhi(hv);
  for (int t = start + half * 4; t < end; t += 8) {
    int4 ia = *(const int4*)&eidx[t];
    float4 pa = *(const float4*)&pcsr[t];
    unsigned hA = *(const unsigned*)&h[(size_t)ia.x * 64 + 2 * c];
    unsigned hB = *(const unsigned*)&h[(size_t)ia.y * 64 + 2 * c];
    unsigned hC = *(const unsigned*)&h[(size_t)ia.z * 64 + 2 * c];
    unsigned hD = *(const unsigned*)&h[(size_t)ia.w * 64 + 2 * c];
    den += (pa.x + pa.y) + (pa.z + pa.w);
    acc0 += (pa.x * bflo(hA) + pa.y * bflo(hB)) + (pa.z * bflo(hC) + pa.w * bflo(hD));
    acc1 += (pa.x * bfhi(hA) + pa.y * bfhi(hB)) + (pa.z * bfhi(hC) + pa.w * bfhi(hD));
  }
  den += __shfl_xor(den, 32);
  acc0 += __shfl_xor(acc0, 32);
  acc1 += __shfl_xor(acc1, 32);
  float vden = den + EPS;
  float2 bv = *(const float2*)&bias[2 * c];
  float v0 = acc0 / vden + bv.x;
  float v1 = acc1 / vden + bv.y;
  v0 = v0 > 0.f ? v0 : expm1f(v0);
  v1 = v1 > 0.f ? v1 : expm1f(v1);
  if (!half) *(float2*)&outp[(size_t)n * 64 + 2 * c] = make_float2(v0, v1);
}

extern "C" void kernel_launch(void* const* d_in, const int* in_sizes, int n_in,
                              void* d_out, int out_size, void* d_ws, size_t ws_size,
                              hipStream_t stream) {
  const float* x = (const float*)d_in[0];
  const int* ei1 = (const int*)d_in[1];
  const int* ei2 = (const int*)d_in[2];
  const float* W2 = (const float*)d_in[3];
  const float* as2 = (const float*)d_in[4];
  const float* ad2 = (const float*)d_in[5];
  const float* b2 = (const float*)d_in[6];
  const float* W1 = (const float*)d_in[7];
  const float* as1 = (const float*)d_in[8];
  const float* ad1 = (const float*)d_in[9];
  const float* b1 = (const float*)d_in[10];
  float* out = (float*)d_out;

  const int N = in_sizes[0] / 128;
  const int E1 = in_sizes[1] / 2;
  const int E2 = in_sizes[2] / 2;
  const int Emax = E1 > E2 ? E1 : E2;
  const size_t Ns = (size_t)N;

  const int nbuck = (N + BUCK_NODES - 1) / BUCK_NODES;  // 391 for N=100k (<= MAXBUCK)
  int lam = (Emax + nbuck - 1) / nbuck;
  int cap = lam + (lam >> 2) + 2048;  // slack: count variance + pad-to-8 worst case
  cap = (cap + 255) & ~(int)255;
  const size_t NC = (size_t)nbuck * cap;

  float* ws = (float*)d_ws;
  size_t o = 0;
  unsigned short* Wb2 = (unsigned short*)(ws + o); o += 8192;   // 16384 bf16
  unsigned short* Wb1 = (unsigned short*)(ws + o); o += 4096;   // 8192 bf16
  float* asrc2 = ws + o;  o += 2 * Ns;
  float* adst2 = ws + o;  o += 2 * Ns;
  float* asrc1 = ws + o;  o += Ns;
  float* adst1 = ws + o;  o += Ns;
  int* gcur2 = (int*)(ws + o);   o += (size_t)nbuck;
  int* gcur1 = (int*)(ws + o);   o += (size_t)nbuck;
  int* rowbeg2 = (int*)(ws + o); o += Ns;
  int* rowend2 = (int*)(ws + o); o += Ns;
  int* rowbeg1 = (int*)(ws + o); o += Ns;
  int* rowend1 = (int*)(ws + o); o += Ns;
  o = (o + 7) & ~(size_t)7;
  int* part = (int*)(ws + o);    o += NC;       // packed (s<<8|d8); shared by both layers
  int* eidx = (int*)(ws + o);    o += NC;       // shared by both layers
  o = (o + 7) & ~(size_t)7;
  float* pcsr = ws + o;          o += 2 * NC;   // l2: float2[NC]; l1: float[NC]
  o = (o + 7) & ~(size_t)7;
  bf16* h2 = (bf16*)(ws + o);    o += 64 * Ns;  // 128N bf16; h1 aliases
  bf16* h1 = h2;
  bf16* hin1 = (bf16*)(ws + o);  o += 64 * Ns;  // 128N bf16

  const size_t smem2 = (size_t)cap * 4 + 4 * 256 * 4 + 2 * 256 * 4 + 64;
  const size_t smem1 = (size_t)cap * 4 + 4 * 256 * 4 + 1 * 256 * 4 + 64;

  // prep
  convert_w<<<(16384 + 8192 + 255) / 256, 256, 0, stream>>>(W2, Wb2, W1, Wb1);
  hipMemsetAsync(gcur2, 0, 2 * (size_t)nbuck * sizeof(int), stream);

  // ---- layer 2: 128 -> [2 heads x 64], concat ----
  partition_kernel<4096><<<(E2 + 4095) / 4096, 256, 0, stream>>>(ei2, E2, gcur2, part, cap, nbuck);
  gemm_att_mfma<128, 2, true, float>
      <<<(N + 63) / 64, 256, 0, stream>>>(x, Wb2, as2, ad2, h2, asrc2, adst2, N);
  csr_build_kernel<2><<<nbuck, 256, smem2, stream>>>(part, gcur2, cap, asrc2, adst2, eidx, pcsr,
                                                     rowbeg2, rowend2, N);
  partition_kernel<4096><<<(E1 + 4095) / 4096, 256, 0, stream>>>(ei1, E1, gcur1, part, cap, nbuck);
  gather2_kernel<<<(N + 3) / 4, 256, 0, stream>>>(h2, asrc2, adst2, rowbeg2, rowend2, eidx, pcsr,
                                                  b2, hin1, N);

  // ---- layer 1: 128 -> 64, single head ----
  gemm_att_mfma<64, 1, false, bf16>
      <<<(N + 63) / 64, 256, 0, stream>>>(hin1, Wb1, as1, ad1, h1, asrc1, adst1, N);
  csr_build_kernel<1><<<nbuck, 256, smem1, stream>>>(part, gcur1, cap, asrc1, adst1, eidx, pcsr,
                                                     rowbeg1, rowend1, N);
  gather1_kernel<<<(N + 3) / 4, 256, 0, stream>>>(h1, asrc1, adst1, rowbeg1, rowend1, eidx, pcsr,
                                                  b1, out, N);
}